// Round 2
// baseline (23071.066 us; speedup 1.0000x reference)
//
#include <hip/hip_runtime.h>
#include <math.h>

#define B_SZ   64
#define TX_SZ  200
#define TY_SZ  100
#define D_MODEL 512
#define H_SZ   8
#define DK_SZ  64
#define DFF_SZ 2048
#define L_SZ   4
#define V_SZ   30

#define NEG_BIG -1.0e30f

// ---------------- LayerNorm (rows x 512) ----------------
__global__ __launch_bounds__(256)
void ln_kernel(const float* __restrict__ in, const float* __restrict__ g,
               const float* __restrict__ b, float* __restrict__ out, int rows) {
    int row = blockIdx.x;
    if (row >= rows) return;
    const float* xr = in + (size_t)row * D_MODEL;
    float s = 0.f, ss = 0.f;
    for (int i = threadIdx.x; i < D_MODEL; i += 256) {
        float v = xr[i];
        s += v; ss += v * v;
    }
    __shared__ float rs[256], rss[256];
    int tid = threadIdx.x;
    rs[tid] = s; rss[tid] = ss;
    __syncthreads();
    for (int w = 128; w > 0; w >>= 1) {
        if (tid < w) { rs[tid] += rs[tid + w]; rss[tid] += rss[tid + w]; }
        __syncthreads();
    }
    float mean = rs[0] * (1.0f / D_MODEL);
    float var  = rss[0] * (1.0f / D_MODEL) - mean * mean;
    float rstd = rsqrtf(var + 1e-5f);
    float* orow = out + (size_t)row * D_MODEL;
    for (int i = tid; i < D_MODEL; i += 256) {
        orow[i] = (xr[i] - mean) * rstd * g[i] + b[i];
    }
}

// ---------------- GEMM: C[M,N] = A[M,K] @ W[N,K]^T (+bias)(+resid)(relu?) ----
// M % 64 == 0, N % 64 == 0, K % 16 == 0.  lda = K, ldc = ldr = N.
__global__ __launch_bounds__(256)
void gemm_kernel(const float* __restrict__ A, int lda,
                 const float* __restrict__ W, int ldw,
                 float* __restrict__ C, int ldc,
                 const float* __restrict__ bias,
                 const float* resid, int ldr,
                 int relu, int M, int N, int K) {
    __shared__ float As[16][64];
    __shared__ float Ws[16][65];
    int tid = threadIdx.x;
    int tx = tid & 15, ty = tid >> 4;
    int n0 = blockIdx.x * 64;
    int m0 = blockIdx.y * 64;
    float acc[4][4] = {};
    for (int k0 = 0; k0 < K; k0 += 16) {
        #pragma unroll
        for (int it = 0; it < 4; ++it) {
            int i = tid + it * 256;
            int r = i >> 4, kk = i & 15;
            As[kk][r] = A[(size_t)(m0 + r) * lda + k0 + kk];
            Ws[kk][r] = W[(size_t)(n0 + r) * ldw + k0 + kk];
        }
        __syncthreads();
        #pragma unroll
        for (int kk = 0; kk < 16; ++kk) {
            float a[4], w[4];
            #pragma unroll
            for (int i = 0; i < 4; ++i) a[i] = As[kk][ty * 4 + i];
            #pragma unroll
            for (int j = 0; j < 4; ++j) w[j] = Ws[kk][tx * 4 + j];
            #pragma unroll
            for (int i = 0; i < 4; ++i)
                #pragma unroll
                for (int j = 0; j < 4; ++j)
                    acc[i][j] += a[i] * w[j];
        }
        __syncthreads();
    }
    #pragma unroll
    for (int i = 0; i < 4; ++i) {
        int m = m0 + ty * 4 + i;
        #pragma unroll
        for (int j = 0; j < 4; ++j) {
            int n = n0 + tx * 4 + j;
            float c = acc[i][j];
            if (bias)  c += bias[n];
            if (resid) c += resid[(size_t)m * ldr + n];
            if (relu)  c = fmaxf(c, 0.f);
            C[(size_t)m * ldc + n] = c;
        }
    }
}

// ---------------- attention: one block per (b,h,t), O written IN-PLACE into Q ----
// Q: [B*T, 512] (col h*64+k), K/V: [B*S, 512].
// Safe in-place: block (b,h,t) reads only Q slice (b,t,h*64..) at start and is the
// only block writing that exact slice.
__global__ __launch_bounds__(256)
void attn_kernel(float* __restrict__ Q, const float* __restrict__ K,
                 const float* __restrict__ V,
                 const int* __restrict__ mask, int T, int S, int causal,
                 float rscale) {
    int blk = blockIdx.x;
    int t = blk % T;
    int tmp = blk / T;
    int h = tmp % H_SZ;
    int b = tmp / H_SZ;
    int tid = threadIdx.x;

    __shared__ float qs[DK_SZ];
    __shared__ float ps[256];
    __shared__ float red[256];

    float* qrow = Q + ((size_t)(b * T + t) * D_MODEL) + h * DK_SZ;
    if (tid < DK_SZ) qs[tid] = qrow[tid];
    __syncthreads();

    int s = tid;
    bool valid = (s < S) && (!causal || s <= t);
    if (valid && mask) valid = (mask[((size_t)b * T + t) * S + s] != 1);
    float score = NEG_BIG;
    if (valid) {
        const float* krow = K + ((size_t)(b * S + s) * D_MODEL) + h * DK_SZ;
        float acc = 0.f;
        #pragma unroll 8
        for (int k = 0; k < DK_SZ; ++k) acc += qs[k] * krow[k];
        score = acc * rscale;
    }
    red[tid] = score;
    __syncthreads();
    for (int w = 128; w > 0; w >>= 1) {
        if (tid < w) red[tid] = fmaxf(red[tid], red[tid + w]);
        __syncthreads();
    }
    float mx = red[0];
    __syncthreads();
    float p = valid ? __expf(score - mx) : 0.f;
    ps[tid] = p;
    red[tid] = p;
    __syncthreads();
    for (int w = 128; w > 0; w >>= 1) {
        if (tid < w) red[tid] += red[tid + w];
        __syncthreads();
    }
    float denom = red[0];
    float rdenom = (denom > 0.f) ? 1.0f / denom : 0.f;
    __syncthreads();

    int dv = tid & 63, quarter = tid >> 6;
    float pacc = 0.f;
    for (int sv = quarter; sv < S; sv += 4)
        pacc += ps[sv] * V[((size_t)(b * S + sv) * D_MODEL) + h * DK_SZ + dv];
    red[tid] = pacc;
    __syncthreads();
    if (tid < 64) {
        float o = (red[tid] + red[tid + 64] + red[tid + 128] + red[tid + 192]) * rdenom;
        qrow[dv] = o;
    }
}

// ---------------- final logits: [rows,512] @ ll_w[30,512]^T + b -> f32 ----------------
__global__ __launch_bounds__(256)
void logits_kernel(const float* __restrict__ X, const float* __restrict__ Wl,
                   const float* __restrict__ bl, float* __restrict__ out, int rows) {
    int idx = blockIdx.x * 256 + threadIdx.x;
    if (idx >= rows * V_SZ) return;
    int row = idx / V_SZ, v = idx % V_SZ;
    const float* xr = X + (size_t)row * D_MODEL;
    const float* wr = Wl + (size_t)v * D_MODEL;
    float acc = bl[v];
    #pragma unroll 8
    for (int k = 0; k < D_MODEL; ++k) acc += xr[k] * wr[k];
    out[idx] = acc;
}

extern "C" void kernel_launch(void* const* d_in, const int* in_sizes, int n_in,
                              void* d_out, int out_size, void* d_ws, size_t ws_size,
                              hipStream_t stream) {
    const float* x          = (const float*)d_in[0];
    const float* y          = (const float*)d_in[1];
    const int*   x_mask     = (const int*)d_in[2];
    const int*   y_mask     = (const int*)d_in[3];
    const float* enc_qkv    = (const float*)d_in[4];
    const float* enc_proj_w = (const float*)d_in[5];
    const float* enc_proj_b = (const float*)d_in[6];
    const float* enc_ln1_g  = (const float*)d_in[7];
    const float* enc_ln1_b  = (const float*)d_in[8];
    const float* enc_ff_w1  = (const float*)d_in[9];
    const float* enc_ff_b1  = (const float*)d_in[10];
    const float* enc_ff_w2  = (const float*)d_in[11];
    const float* enc_ff_b2  = (const float*)d_in[12];
    const float* enc_ln2_g  = (const float*)d_in[13];
    const float* enc_ln2_b  = (const float*)d_in[14];
    const float* dec_sa_qkv    = (const float*)d_in[15];
    const float* dec_sa_proj_w = (const float*)d_in[16];
    const float* dec_sa_proj_b = (const float*)d_in[17];
    const float* dec_ln1_g  = (const float*)d_in[18];
    const float* dec_ln1_b  = (const float*)d_in[19];
    const float* dec_ca_qkv    = (const float*)d_in[20];
    const float* dec_ca_proj_w = (const float*)d_in[21];
    const float* dec_ca_proj_b = (const float*)d_in[22];
    const float* dec_ln2_g  = (const float*)d_in[23];
    const float* dec_ln2_b  = (const float*)d_in[24];
    const float* dec_ff_w1  = (const float*)d_in[25];
    const float* dec_ff_b1  = (const float*)d_in[26];
    const float* dec_ff_w2  = (const float*)d_in[27];
    const float* dec_ff_b2  = (const float*)d_in[28];
    const float* dec_ln3_g  = (const float*)d_in[29];
    const float* dec_ln3_b  = (const float*)d_in[30];
    const float* ll_w       = (const float*)d_in[31];
    const float* ll_b       = (const float*)d_in[32];

    const int ME = B_SZ * TX_SZ;   // 12800 encoder rows
    const int MD = B_SZ * TY_SZ;   // 6400 decoder rows
    const float rscale = 1.0f / sqrtf((float)D_MODEL);  // scale uses d_model per reference

    // workspace layout (fp32) — total 7*ME_ish ≈ 39.3M floats ≈ 157 MB
    float* ws = (float*)d_ws;
    size_t off = 0;
    auto alloc = [&](size_t n) { float* p = ws + off; off += n; return p; };
    float* A_enc = alloc((size_t)ME * D_MODEL);
    float* A_dec = alloc((size_t)MD * D_MODEL);
    float* N1    = alloc((size_t)ME * D_MODEL);
    float* NQ    = alloc((size_t)MD * D_MODEL);
    float* Qb    = alloc((size_t)ME * D_MODEL);
    float* Kb    = alloc((size_t)ME * D_MODEL);
    float* Vb    = alloc((size_t)ME * D_MODEL);
    float* Hb    = Qb;  // FF hidden chunk reuses Q buffer (disjoint in time)

    auto gemm = [&](const float* A, const float* W, int ldw, float* C,
                    const float* bias, const float* resid, int relu,
                    int M, int N, int K) {
        dim3 grid(N / 64, M / 64);
        hipLaunchKernelGGL(gemm_kernel, grid, dim3(256), 0, stream,
                           A, K, W, ldw, C, N, bias, resid, N, relu, M, N, K);
    };
    auto ln = [&](const float* in, const float* g, const float* b, float* out, int rows) {
        hipLaunchKernelGGL(ln_kernel, dim3(rows), dim3(256), 0, stream, in, g, b, out, rows);
    };
    auto attn = [&](float* Q, const float* K, const float* V,
                    const int* mask, int T, int S, int causal) {
        hipLaunchKernelGGL(attn_kernel, dim3(B_SZ * H_SZ * T), dim3(256), 0, stream,
                           Q, K, V, mask, T, S, causal, rscale);
    };

    const int WQKV = 3 * D_MODEL * D_MODEL;   // per-layer qkv stride
    const int WDD  = D_MODEL * D_MODEL;
    const int CH   = 512;                     // DFF chunk width (4 chunks)

    // ---------------- encoder ----------------
    for (int l = 0; l < L_SZ; ++l) {
        const float* src = (l == 0) ? x : A_enc;
        ln(src, enc_ln1_g + l * D_MODEL, enc_ln1_b + l * D_MODEL, N1, ME);
        const float* qkv = enc_qkv + (size_t)l * WQKV;
        gemm(N1, qkv + 0 * WDD, D_MODEL, Qb, nullptr, nullptr, 0, ME, D_MODEL, D_MODEL);
        gemm(N1, qkv + 1 * WDD, D_MODEL, Kb, nullptr, nullptr, 0, ME, D_MODEL, D_MODEL);
        gemm(N1, qkv + 2 * WDD, D_MODEL, Vb, nullptr, nullptr, 0, ME, D_MODEL, D_MODEL);
        attn(Qb, Kb, Vb, x_mask, TX_SZ, TX_SZ, 0);
        gemm(Qb, enc_proj_w + (size_t)l * WDD, D_MODEL, A_enc,
             enc_proj_b + l * D_MODEL, N1, 0, ME, D_MODEL, D_MODEL);
        // FF
        ln(A_enc, enc_ln2_g + l * D_MODEL, enc_ln2_b + l * D_MODEL, N1, ME);
        for (int c = 0; c < DFF_SZ / CH; ++c) {
            const float* w1 = enc_ff_w1 + (size_t)l * DFF_SZ * D_MODEL + (size_t)c * CH * D_MODEL;
            const float* b1 = enc_ff_b1 + (size_t)l * DFF_SZ + c * CH;
            gemm(N1, w1, D_MODEL, Hb, b1, nullptr, 1, ME, CH, D_MODEL);
            const float* w2 = enc_ff_w2 + (size_t)l * D_MODEL * DFF_SZ + c * CH;
            const float* b2 = (c == 0) ? enc_ff_b2 + l * D_MODEL : nullptr;
            gemm(Hb, w2, DFF_SZ, A_enc, b2, A_enc, 0, ME, D_MODEL, CH);
        }
    }

    // ---------------- decoder ----------------
    for (int l = 0; l < L_SZ; ++l) {
        // self-attention (causal, y_mask)
        const float* src = (l == 0) ? y : A_dec;
        ln(src, dec_ln1_g + l * D_MODEL, dec_ln1_b + l * D_MODEL, N1, MD);
        const float* qkv = dec_sa_qkv + (size_t)l * WQKV;
        gemm(N1, qkv + 0 * WDD, D_MODEL, Qb, nullptr, nullptr, 0, MD, D_MODEL, D_MODEL);
        gemm(N1, qkv + 1 * WDD, D_MODEL, Kb, nullptr, nullptr, 0, MD, D_MODEL, D_MODEL);
        gemm(N1, qkv + 2 * WDD, D_MODEL, Vb, nullptr, nullptr, 0, MD, D_MODEL, D_MODEL);
        attn(Qb, Kb, Vb, y_mask, TY_SZ, TY_SZ, 1);
        gemm(Qb, dec_sa_proj_w + (size_t)l * WDD, D_MODEL, A_dec,
             dec_sa_proj_b + l * D_MODEL, N1, 0, MD, D_MODEL, D_MODEL);
        // cross-attention (k=v=enc normed, q=dec normed; same LN params on both)
        ln(A_enc, dec_ln2_g + l * D_MODEL, dec_ln2_b + l * D_MODEL, N1, ME);
        ln(A_dec, dec_ln2_g + l * D_MODEL, dec_ln2_b + l * D_MODEL, NQ, MD);
        const float* cqkv = dec_ca_qkv + (size_t)l * WQKV;
        gemm(NQ, cqkv + 0 * WDD, D_MODEL, Qb, nullptr, nullptr, 0, MD, D_MODEL, D_MODEL);
        gemm(N1, cqkv + 1 * WDD, D_MODEL, Kb, nullptr, nullptr, 0, ME, D_MODEL, D_MODEL);
        gemm(N1, cqkv + 2 * WDD, D_MODEL, Vb, nullptr, nullptr, 0, ME, D_MODEL, D_MODEL);
        attn(Qb, Kb, Vb, nullptr, TY_SZ, TX_SZ, 0);
        gemm(Qb, dec_ca_proj_w + (size_t)l * WDD, D_MODEL, A_dec,
             dec_ca_proj_b + l * D_MODEL, NQ, 0, MD, D_MODEL, D_MODEL);
        // FF
        ln(A_dec, dec_ln3_g + l * D_MODEL, dec_ln3_b + l * D_MODEL, N1, MD);
        for (int c = 0; c < DFF_SZ / CH; ++c) {
            const float* w1 = dec_ff_w1 + (size_t)l * DFF_SZ * D_MODEL + (size_t)c * CH * D_MODEL;
            const float* b1 = dec_ff_b1 + (size_t)l * DFF_SZ + c * CH;
            gemm(N1, w1, D_MODEL, Hb, b1, nullptr, 1, MD, CH, D_MODEL);
            const float* w2 = dec_ff_w2 + (size_t)l * D_MODEL * DFF_SZ + c * CH;
            const float* b2 = (c == 0) ? dec_ff_b2 + l * D_MODEL : nullptr;
            gemm(Hb, w2, DFF_SZ, A_dec, b2, A_dec, 0, MD, D_MODEL, CH);
        }
    }

    // ---------------- final projection ----------------
    {
        int total = MD * V_SZ;
        hipLaunchKernelGGL(logits_kernel, dim3((total + 255) / 256), dim3(256), 0, stream,
                           A_dec, ll_w, ll_b, (float*)d_out, MD);
    }
    (void)in_sizes; (void)n_in; (void)out_size; (void)ws_size;
}

// Round 3
// 18075.275 us; speedup vs baseline: 1.2764x; 1.2764x over previous
//
#include <hip/hip_runtime.h>
#include <math.h>

#define B_SZ   64
#define TX_SZ  200
#define TY_SZ  100
#define D_MODEL 512
#define H_SZ   8
#define DK_SZ  64
#define DFF_SZ 2048
#define L_SZ   4
#define V_SZ   30

#define NEG_BIG -1.0e30f

typedef unsigned short u16;
typedef __attribute__((ext_vector_type(8))) short short8;
typedef __attribute__((ext_vector_type(4))) float f32x4;

__device__ __forceinline__ float b2f(u16 h) {
    union { unsigned int u; float f; } v; v.u = ((unsigned int)h) << 16; return v.f;
}
__device__ __forceinline__ u16 f2b(float f) {
    union { float f; unsigned int u; } v; v.f = f;
    unsigned int r = v.u + 0x7fffu + ((v.u >> 16) & 1u);
    return (u16)(r >> 16);
}

#define GLD16(gp, lp) __builtin_amdgcn_global_load_lds( \
    (const __attribute__((address_space(1))) unsigned int*)(gp), \
    (__attribute__((address_space(3))) unsigned int*)(lp), 16, 0, 0)

// ---------------- cast f32 -> bf16 ----------------
__global__ __launch_bounds__(256)
void castw_kernel(const float* __restrict__ in, u16* __restrict__ out, int n) {
    int i = blockIdx.x * 256 + threadIdx.x;
    if (i < n) out[i] = f2b(in[i]);
}

// ---------------- LayerNorm (rows x 512), dual f32/bf16 output ----------------
__global__ __launch_bounds__(256)
void ln_kernel(const float* __restrict__ in, const float* __restrict__ g,
               const float* __restrict__ b, float* outf, u16* outb, int rows) {
    int row = blockIdx.x;
    if (row >= rows) return;
    const float* xr = in + (size_t)row * D_MODEL;
    float s = 0.f, ss = 0.f;
    for (int i = threadIdx.x; i < D_MODEL; i += 256) {
        float v = xr[i];
        s += v; ss += v * v;
    }
    __shared__ float rs[256], rss[256];
    int tid = threadIdx.x;
    rs[tid] = s; rss[tid] = ss;
    __syncthreads();
    for (int w = 128; w > 0; w >>= 1) {
        if (tid < w) { rs[tid] += rs[tid + w]; rss[tid] += rss[tid + w]; }
        __syncthreads();
    }
    float mean = rs[0] * (1.0f / D_MODEL);
    float var  = rss[0] * (1.0f / D_MODEL) - mean * mean;
    float rstd = rsqrtf(var + 1e-5f);
    for (int i = tid; i < D_MODEL; i += 256) {
        float o = (xr[i] - mean) * rstd * g[i] + b[i];
        if (outf) outf[(size_t)row * D_MODEL + i] = o;
        if (outb) outb[(size_t)row * D_MODEL + i] = f2b(o);
    }
}

// ---------------- MFMA GEMM: C[M,N] = A[M,K](bf16) @ W[N,K](bf16)^T ------------
// 128x128 tile, BK=32, global_load_lds staging, mfma_f32_16x16x32_bf16.
// Epilogue: +bias(f32), +resid(f32), relu, write f32 and/or bf16.
__global__ __launch_bounds__(256)
void gemm_mfma(const u16* __restrict__ A, int lda,
               const u16* __restrict__ W, int ldw,
               float* outf, int ldcf, u16* outb, int ldcb,
               const float* __restrict__ bias,
               const float* __restrict__ resid, int ldr,
               int relu, int K) {
    __shared__ u16 Alds[128 * 32];
    __shared__ u16 Blds[128 * 32];
    const int tid  = threadIdx.x;
    const int wave = tid >> 6, lane = tid & 63;
    const int lr = lane & 15, lq = lane >> 4;
    const int wm = (wave >> 1) * 64, wn = (wave & 1) * 64;
    const int m0 = blockIdx.y * 128, n0 = blockIdx.x * 128;
    const int grow = tid >> 2;          // 0..63
    const int gcol = (tid & 3) * 8;     // 0,8,16,24
    const int woff = wave * 512;        // shorts: per-wave 1 KB chunk

    f32x4 zero = {0.f, 0.f, 0.f, 0.f};
    f32x4 acc[4][4];
    #pragma unroll
    for (int i = 0; i < 4; ++i)
        #pragma unroll
        for (int j = 0; j < 4; ++j) acc[i][j] = zero;

    const u16* Ag = A + (size_t)m0 * lda;
    const u16* Wg = W + (size_t)n0 * ldw;

    for (int k0 = 0; k0 < K; k0 += 32) {
        GLD16(Ag + (size_t)grow * lda + k0 + gcol,        &Alds[woff]);
        GLD16(Ag + (size_t)(64 + grow) * lda + k0 + gcol, &Alds[2048 + woff]);
        GLD16(Wg + (size_t)grow * ldw + k0 + gcol,        &Blds[woff]);
        GLD16(Wg + (size_t)(64 + grow) * ldw + k0 + gcol, &Blds[2048 + woff]);
        __syncthreads();
        short8 af[4], bfr[4];
        #pragma unroll
        for (int i = 0; i < 4; ++i)
            af[i] = *(const short8*)&Alds[(wm + i * 16 + lr) * 32 + lq * 8];
        #pragma unroll
        for (int j = 0; j < 4; ++j)
            bfr[j] = *(const short8*)&Blds[(wn + j * 16 + lr) * 32 + lq * 8];
        #pragma unroll
        for (int i = 0; i < 4; ++i)
            #pragma unroll
            for (int j = 0; j < 4; ++j)
                acc[i][j] = __builtin_amdgcn_mfma_f32_16x16x32_bf16(af[i], bfr[j], acc[i][j], 0, 0, 0);
        __syncthreads();
    }

    #pragma unroll
    for (int i = 0; i < 4; ++i) {
        #pragma unroll
        for (int r = 0; r < 4; ++r) {
            int m = m0 + wm + i * 16 + lq * 4 + r;
            #pragma unroll
            for (int j = 0; j < 4; ++j) {
                int n = n0 + wn + j * 16 + lr;
                float c = acc[i][j][r];
                if (bias)  c += bias[n];
                if (resid) c += resid[(size_t)m * ldr + n];
                if (relu)  c = fmaxf(c, 0.f);
                if (outf) outf[(size_t)m * ldcf + n] = c;
                if (outb) outb[(size_t)m * ldcb + n] = f2b(c);
            }
        }
    }
}

// ---------------- attention: block per (b,h,t), coalesced, bf16 in/out ----------
// O written in-place into the Q slice (only this block touches that slice).
__global__ __launch_bounds__(256)
void attn_kernel(u16* __restrict__ Q, int ldq, const u16* __restrict__ K, int ldk,
                 const u16* __restrict__ V, int ldv,
                 const int* __restrict__ mask, int T, int S, int causal, float rscale) {
    int blk = blockIdx.x;
    int t = blk % T;
    int tmp = blk / T;
    int h = tmp % H_SZ;
    int b = tmp / H_SZ;
    int tid = threadIdx.x, wave = tid >> 6, lane = tid & 63;

    __shared__ float qs[DK_SZ];
    __shared__ float ps[256];
    __shared__ float red[256];

    u16* qrow = Q + (size_t)(b * T + t) * ldq + h * DK_SZ;
    if (tid < DK_SZ) qs[tid] = b2f(qrow[tid]);
    __syncthreads();

    float qv = qs[lane];
    const u16* Kb = K + (size_t)(b * S) * ldk + h * DK_SZ;
    for (int s = wave; s < S; s += 4) {
        float kv = b2f(Kb[(size_t)s * ldk + lane]);
        float prod = qv * kv;
        #pragma unroll
        for (int off = 32; off > 0; off >>= 1) prod += __shfl_down(prod, off, 64);
        if (lane == 0) {
            bool valid = (!causal || s <= t);
            if (valid && mask) valid = (mask[((size_t)b * T + t) * S + s] != 1);
            ps[s] = valid ? prod * rscale : NEG_BIG;
        }
    }
    __syncthreads();

    red[tid] = (tid < S) ? ps[tid] : NEG_BIG;
    __syncthreads();
    for (int w = 128; w > 0; w >>= 1) {
        if (tid < w) red[tid] = fmaxf(red[tid], red[tid + w]);
        __syncthreads();
    }
    float mx = red[0];
    __syncthreads();
    float p = 0.f;
    if (tid < S) {
        p = (ps[tid] > 0.5f * NEG_BIG) ? __expf(ps[tid] - mx) : 0.f;
        ps[tid] = p;
    }
    red[tid] = p;
    __syncthreads();
    for (int w = 128; w > 0; w >>= 1) {
        if (tid < w) red[tid] += red[tid + w];
        __syncthreads();
    }
    float denom = red[0];
    float rden = (denom > 0.f) ? 1.0f / denom : 0.f;
    __syncthreads();

    const u16* Vb = V + (size_t)(b * S) * ldv + h * DK_SZ;
    float pacc = 0.f;
    for (int s = wave; s < S; s += 4)
        pacc += ps[s] * b2f(Vb[(size_t)s * ldv + lane]);
    red[tid] = pacc;
    __syncthreads();
    if (tid < DK_SZ) {
        float o = (red[tid] + red[tid + 64] + red[tid + 128] + red[tid + 192]) * rden;
        qrow[tid] = f2b(o);
    }
}

// ---------------- final logits: [rows,512](f32) @ ll_w[30,512]^T + b -> f32 ------
__global__ __launch_bounds__(256)
void logits_kernel(const float* __restrict__ X, const float* __restrict__ Wl,
                   const float* __restrict__ bl, float* __restrict__ out, int rows) {
    int idx = blockIdx.x * 256 + threadIdx.x;
    if (idx >= rows * V_SZ) return;
    int row = idx / V_SZ, v = idx % V_SZ;
    const float* xr = X + (size_t)row * D_MODEL;
    const float* wr = Wl + (size_t)v * D_MODEL;
    float acc = bl[v];
    #pragma unroll 8
    for (int k = 0; k < D_MODEL; ++k) acc += xr[k] * wr[k];
    out[idx] = acc;
}

extern "C" void kernel_launch(void* const* d_in, const int* in_sizes, int n_in,
                              void* d_out, int out_size, void* d_ws, size_t ws_size,
                              hipStream_t stream) {
    const float* x          = (const float*)d_in[0];
    const float* y          = (const float*)d_in[1];
    const int*   x_mask     = (const int*)d_in[2];
    const int*   y_mask     = (const int*)d_in[3];
    const float* enc_qkv    = (const float*)d_in[4];
    const float* enc_proj_w = (const float*)d_in[5];
    const float* enc_proj_b = (const float*)d_in[6];
    const float* enc_ln1_g  = (const float*)d_in[7];
    const float* enc_ln1_b  = (const float*)d_in[8];
    const float* enc_ff_w1  = (const float*)d_in[9];
    const float* enc_ff_b1  = (const float*)d_in[10];
    const float* enc_ff_w2  = (const float*)d_in[11];
    const float* enc_ff_b2  = (const float*)d_in[12];
    const float* enc_ln2_g  = (const float*)d_in[13];
    const float* enc_ln2_b  = (const float*)d_in[14];
    const float* dec_sa_qkv    = (const float*)d_in[15];
    const float* dec_sa_proj_w = (const float*)d_in[16];
    const float* dec_sa_proj_b = (const float*)d_in[17];
    const float* dec_ln1_g  = (const float*)d_in[18];
    const float* dec_ln1_b  = (const float*)d_in[19];
    const float* dec_ca_qkv    = (const float*)d_in[20];
    const float* dec_ca_proj_w = (const float*)d_in[21];
    const float* dec_ca_proj_b = (const float*)d_in[22];
    const float* dec_ln2_g  = (const float*)d_in[23];
    const float* dec_ln2_b  = (const float*)d_in[24];
    const float* dec_ff_w1  = (const float*)d_in[25];
    const float* dec_ff_b1  = (const float*)d_in[26];
    const float* dec_ff_w2  = (const float*)d_in[27];
    const float* dec_ff_b2  = (const float*)d_in[28];
    const float* dec_ln3_g  = (const float*)d_in[29];
    const float* dec_ln3_b  = (const float*)d_in[30];
    const float* ll_w       = (const float*)d_in[31];
    const float* ll_b       = (const float*)d_in[32];

    const int ME = B_SZ * TX_SZ;   // 12800
    const int MD = B_SZ * TY_SZ;   // 6400
    const float rscale = 1.0f / sqrtf((float)D_MODEL);

    // ---- workspace (bytes, 64-aligned) — total ~142 MB ----
    char* base = (char*)d_ws;
    size_t off = 0;
    auto alloc = [&](size_t bytes) {
        void* p = base + off;
        off = (off + bytes + 63) & ~(size_t)63;
        return p;
    };
    float* A_enc = (float*)alloc((size_t)ME * D_MODEL * 4);
    float* A_dec = (float*)alloc((size_t)MD * D_MODEL * 4);
    float* N1f   = (float*)alloc((size_t)ME * D_MODEL * 4);
    u16*   N1b   = (u16*)  alloc((size_t)ME * D_MODEL * 2);
    u16*   NQb   = (u16*)  alloc((size_t)MD * D_MODEL * 2);
    u16*   BIG   = (u16*)  alloc((size_t)ME * DFF_SZ * 2);   // QKVb / Hb / KVb+Qca union
    u16*   Wa    = (u16*)  alloc((size_t)DFF_SZ * D_MODEL * 2);
    u16*   Wb2   = (u16*)  alloc((size_t)DFF_SZ * D_MODEL * 2);
    u16* QKVb = BIG;                        // [M,1536]
    u16* Hb   = BIG;                        // [M,2048]
    u16* KVb  = BIG;                        // [ME,1024]
    u16* Qca  = BIG + (size_t)ME * 1024;    // [MD,512]

    auto castw = [&](const float* in, u16* out, int n) {
        hipLaunchKernelGGL(castw_kernel, dim3((n + 255) / 256), dim3(256), 0, stream, in, out, n);
    };
    auto ln = [&](const float* in, const float* g, const float* b,
                  float* outf, u16* outb, int rows) {
        hipLaunchKernelGGL(ln_kernel, dim3(rows), dim3(256), 0, stream, in, g, b, outf, outb, rows);
    };
    auto gemm = [&](const u16* A, int lda, const u16* W, int ldw, int M, int N, int K,
                    float* outf, int ldcf, u16* outb, int ldcb,
                    const float* bias, const float* resid, int ldr, int relu) {
        dim3 grid(N / 128, M / 128);
        hipLaunchKernelGGL(gemm_mfma, grid, dim3(256), 0, stream,
                           A, lda, W, ldw, outf, ldcf, outb, ldcb, bias, resid, ldr, relu, K);
    };
    auto attn = [&](u16* Q, int ldq, const u16* K, int ldk, const u16* V, int ldv,
                    const int* mask, int T, int S, int causal) {
        hipLaunchKernelGGL(attn_kernel, dim3(B_SZ * H_SZ * T), dim3(256), 0, stream,
                           Q, ldq, K, ldk, V, ldv, mask, T, S, causal, rscale);
    };

    const int WQKV = 3 * D_MODEL * D_MODEL;   // 786432
    const int WDD  = D_MODEL * D_MODEL;       // 262144
    const int WFF  = DFF_SZ * D_MODEL;        // 1048576

    // ---------------- encoder ----------------
    for (int l = 0; l < L_SZ; ++l) {
        const float* src = (l == 0) ? x : A_enc;
        castw(enc_qkv + (size_t)l * WQKV, Wa, WQKV);
        ln(src, enc_ln1_g + l * D_MODEL, enc_ln1_b + l * D_MODEL, N1f, N1b, ME);
        gemm(N1b, 512, Wa, 512, ME, 1536, 512, nullptr, 0, QKVb, 1536, nullptr, nullptr, 0, 0);
        attn(QKVb, 1536, QKVb + 512, 1536, QKVb + 1024, 1536, x_mask, TX_SZ, TX_SZ, 0);
        castw(enc_proj_w + (size_t)l * WDD, Wa, WDD);
        gemm(QKVb, 1536, Wa, 512, ME, 512, 512, A_enc, 512, nullptr, 0,
             enc_proj_b + l * D_MODEL, N1f, 512, 0);
        // FF
        ln(A_enc, enc_ln2_g + l * D_MODEL, enc_ln2_b + l * D_MODEL, nullptr, N1b, ME);
        castw(enc_ff_w1 + (size_t)l * WFF, Wa, WFF);
        gemm(N1b, 512, Wa, 512, ME, 2048, 512, nullptr, 0, Hb, 2048,
             enc_ff_b1 + l * DFF_SZ, nullptr, 0, 1);
        castw(enc_ff_w2 + (size_t)l * WFF, Wb2, WFF);
        gemm(Hb, 2048, Wb2, 2048, ME, 512, 2048, A_enc, 512, nullptr, 0,
             enc_ff_b2 + l * D_MODEL, A_enc, 512, 0);
    }

    // ---------------- decoder ----------------
    for (int l = 0; l < L_SZ; ++l) {
        // self-attention (causal, y_mask)
        const float* src = (l == 0) ? y : A_dec;
        castw(dec_sa_qkv + (size_t)l * WQKV, Wa, WQKV);
        ln(src, dec_ln1_g + l * D_MODEL, dec_ln1_b + l * D_MODEL, N1f, N1b, MD);
        gemm(N1b, 512, Wa, 512, MD, 1536, 512, nullptr, 0, QKVb, 1536, nullptr, nullptr, 0, 0);
        attn(QKVb, 1536, QKVb + 512, 1536, QKVb + 1024, 1536, y_mask, TY_SZ, TY_SZ, 1);
        castw(dec_sa_proj_w + (size_t)l * WDD, Wa, WDD);
        gemm(QKVb, 1536, Wa, 512, MD, 512, 512, A_dec, 512, nullptr, 0,
             dec_sa_proj_b + l * D_MODEL, N1f, 512, 0);
        // cross-attention
        ln(A_enc, dec_ln2_g + l * D_MODEL, dec_ln2_b + l * D_MODEL, nullptr, N1b, ME);
        ln(A_dec, dec_ln2_g + l * D_MODEL, dec_ln2_b + l * D_MODEL, N1f, NQb, MD);
        castw(dec_ca_qkv + (size_t)l * WQKV, Wa, WDD);          // Q weights
        gemm(NQb, 512, Wa, 512, MD, 512, 512, nullptr, 0, Qca, 512, nullptr, nullptr, 0, 0);
        castw(dec_ca_qkv + (size_t)l * WQKV + WDD, Wa, 2 * WDD); // K,V weights
        gemm(N1b, 512, Wa, 512, ME, 1024, 512, nullptr, 0, KVb, 1024, nullptr, nullptr, 0, 0);
        attn(Qca, 512, KVb, 1024, KVb + 512, 1024, nullptr, TY_SZ, TX_SZ, 0);
        castw(dec_ca_proj_w + (size_t)l * WDD, Wa, WDD);
        gemm(Qca, 512, Wa, 512, MD, 512, 512, A_dec, 512, nullptr, 0,
             dec_ca_proj_b + l * D_MODEL, N1f, 512, 0);
        // FF
        ln(A_dec, dec_ln3_g + l * D_MODEL, dec_ln3_b + l * D_MODEL, nullptr, N1b, MD);
        castw(dec_ff_w1 + (size_t)l * WFF, Wa, WFF);
        gemm(N1b, 512, Wa, 512, MD, 2048, 512, nullptr, 0, Hb, 2048,
             dec_ff_b1 + l * DFF_SZ, nullptr, 0, 1);
        castw(dec_ff_w2 + (size_t)l * WFF, Wb2, WFF);
        gemm(Hb, 2048, Wb2, 2048, MD, 512, 2048, A_dec, 512, nullptr, 0,
             dec_ff_b2 + l * D_MODEL, A_dec, 512, 0);
    }

    // ---------------- final projection ----------------
    {
        int total = MD * V_SZ;
        hipLaunchKernelGGL(logits_kernel, dim3((total + 255) / 256), dim3(256), 0, stream,
                           A_dec, ll_w, ll_b, (float*)d_out, MD);
    }
    (void)in_sizes; (void)n_in; (void)out_size; (void)ws_size;
}

// Round 4
// 6131.778 us; speedup vs baseline: 3.7625x; 2.9478x over previous
//
#include <hip/hip_runtime.h>
#include <math.h>

#define B_SZ   64
#define TX_SZ  200
#define TY_SZ  100
#define D_MODEL 512
#define H_SZ   8
#define DK_SZ  64
#define DFF_SZ 2048
#define L_SZ   4
#define V_SZ   30

#define NEG_BIG -1.0e30f
#define SMAX 200
#define SPAD 202   /* SMAX+2; SPAD/2 odd => conflict-free transposed staging */

typedef unsigned short u16;
typedef __attribute__((ext_vector_type(8))) short short8;
typedef __attribute__((ext_vector_type(4))) float f32x4;
typedef __attribute__((ext_vector_type(4))) unsigned short u16x4;

__device__ __forceinline__ float b2f(u16 h) {
    union { unsigned int u; float f; } v; v.u = ((unsigned int)h) << 16; return v.f;
}
__device__ __forceinline__ u16 f2b(float f) {
    union { float f; unsigned int u; } v; v.f = f;
    unsigned int r = v.u + 0x7fffu + ((v.u >> 16) & 1u);
    return (u16)(r >> 16);
}

#define GLD16(gp, lp) __builtin_amdgcn_global_load_lds( \
    (const __attribute__((address_space(1))) unsigned int*)(gp), \
    (__attribute__((address_space(3))) unsigned int*)(lp), 16, 0, 0)

// ---------------- cast f32 -> bf16, 4 elems/thread ----------------
__global__ __launch_bounds__(256)
void castw_kernel(const float* __restrict__ in, u16* __restrict__ out, int n4) {
    int i = blockIdx.x * 256 + threadIdx.x;
    if (i < n4) {
        f32x4 v = ((const f32x4*)in)[i];
        u16x4 o;
        o.x = f2b(v.x); o.y = f2b(v.y); o.z = f2b(v.z); o.w = f2b(v.w);
        ((u16x4*)out)[i] = o;
    }
}

// ---------------- LayerNorm (rows x 512), dual f32/bf16 output ----------------
__global__ __launch_bounds__(256)
void ln_kernel(const float* __restrict__ in, const float* __restrict__ g,
               const float* __restrict__ b, float* outf, u16* outb, int rows) {
    int row = blockIdx.x;
    if (row >= rows) return;
    const float* xr = in + (size_t)row * D_MODEL;
    float s = 0.f, ss = 0.f;
    for (int i = threadIdx.x; i < D_MODEL; i += 256) {
        float v = xr[i];
        s += v; ss += v * v;
    }
    __shared__ float rs[256], rss[256];
    int tid = threadIdx.x;
    rs[tid] = s; rss[tid] = ss;
    __syncthreads();
    for (int w = 128; w > 0; w >>= 1) {
        if (tid < w) { rs[tid] += rs[tid + w]; rss[tid] += rss[tid + w]; }
        __syncthreads();
    }
    float mean = rs[0] * (1.0f / D_MODEL);
    float var  = rss[0] * (1.0f / D_MODEL) - mean * mean;
    float rstd = rsqrtf(var + 1e-5f);
    for (int i = tid; i < D_MODEL; i += 256) {
        float o = (xr[i] - mean) * rstd * g[i] + b[i];
        if (outf) outf[(size_t)row * D_MODEL + i] = o;
        if (outb) outb[(size_t)row * D_MODEL + i] = f2b(o);
    }
}

// ---------------- MFMA GEMM: C[M,N] = A[M,K](bf16) @ W[N,K](bf16)^T ------------
__global__ __launch_bounds__(256)
void gemm_mfma(const u16* __restrict__ A, int lda,
               const u16* __restrict__ W, int ldw,
               float* outf, int ldcf, u16* outb, int ldcb,
               const float* __restrict__ bias,
               const float* __restrict__ resid, int ldr,
               int relu, int K) {
    __shared__ u16 Alds[128 * 32];
    __shared__ u16 Blds[128 * 32];
    const int tid  = threadIdx.x;
    const int wave = tid >> 6, lane = tid & 63;
    const int lr = lane & 15, lq = lane >> 4;
    const int wm = (wave >> 1) * 64, wn = (wave & 1) * 64;
    const int m0 = blockIdx.y * 128, n0 = blockIdx.x * 128;
    const int grow = tid >> 2;          // 0..63
    const int gcol = (tid & 3) * 8;     // 0,8,16,24
    const int woff = wave * 512;        // shorts

    f32x4 zero = {0.f, 0.f, 0.f, 0.f};
    f32x4 acc[4][4];
    #pragma unroll
    for (int i = 0; i < 4; ++i)
        #pragma unroll
        for (int j = 0; j < 4; ++j) acc[i][j] = zero;

    const u16* Ag = A + (size_t)m0 * lda;
    const u16* Wg = W + (size_t)n0 * ldw;

    for (int k0 = 0; k0 < K; k0 += 32) {
        GLD16(Ag + (size_t)grow * lda + k0 + gcol,        &Alds[woff]);
        GLD16(Ag + (size_t)(64 + grow) * lda + k0 + gcol, &Alds[2048 + woff]);
        GLD16(Wg + (size_t)grow * ldw + k0 + gcol,        &Blds[woff]);
        GLD16(Wg + (size_t)(64 + grow) * ldw + k0 + gcol, &Blds[2048 + woff]);
        __syncthreads();
        short8 af[4], bfr[4];
        #pragma unroll
        for (int i = 0; i < 4; ++i)
            af[i] = *(const short8*)&Alds[(wm + i * 16 + lr) * 32 + lq * 8];
        #pragma unroll
        for (int j = 0; j < 4; ++j)
            bfr[j] = *(const short8*)&Blds[(wn + j * 16 + lr) * 32 + lq * 8];
        #pragma unroll
        for (int i = 0; i < 4; ++i)
            #pragma unroll
            for (int j = 0; j < 4; ++j)
                acc[i][j] = __builtin_amdgcn_mfma_f32_16x16x32_bf16(af[i], bfr[j], acc[i][j], 0, 0, 0);
        __syncthreads();
    }

    #pragma unroll
    for (int i = 0; i < 4; ++i) {
        #pragma unroll
        for (int r = 0; r < 4; ++r) {
            int m = m0 + wm + i * 16 + lq * 4 + r;
            #pragma unroll
            for (int j = 0; j < 4; ++j) {
                int n = n0 + wn + j * 16 + lr;
                float c = acc[i][j][r];
                if (bias)  c += bias[n];
                if (resid) c += resid[(size_t)m * ldr + n];
                if (relu)  c = fmaxf(c, 0.f);
                if (outf) outf[(size_t)m * ldcf + n] = c;
                if (outb) outb[(size_t)m * ldcb + n] = f2b(c);
            }
        }
    }
}

// ---------------- attention v3: block per (b,h), K/V in LDS, wave per query ----
// O written in-place into Q slice (block exclusively owns its (b,h) slice;
// each wave reads q[t] before writing o[t]).
__global__ __launch_bounds__(256)
void attn_kernel(u16* __restrict__ Q, int ldq, const u16* __restrict__ K, int ldk,
                 const u16* __restrict__ V, int ldv,
                 const int* __restrict__ mask, int T, int S, int causal, float rscale) {
    int bh = blockIdx.x;
    int h = bh % H_SZ, b = bh / H_SZ;
    int tid = threadIdx.x, wave = tid >> 6, lane = tid & 63;

    __shared__ u16 Kt[DK_SZ * SPAD];     // [k][s] transposed, pad for banks
    __shared__ u16 Vl[SMAX * DK_SZ];     // [s][dv]
    __shared__ float ps[4][SPAD];        // per-wave probabilities

    const u16* Kg = K + (size_t)(b * S) * ldk + h * DK_SZ;
    const u16* Vg = V + (size_t)(b * S) * ldv + h * DK_SZ;
    for (int i = tid; i < S * DK_SZ; i += 256) {
        int s = i >> 6, k = i & 63;
        Kt[k * SPAD + s] = Kg[(size_t)s * ldk + k];
        Vl[i] = Vg[(size_t)s * ldv + k];
    }
    __syncthreads();

    const int* mbase = mask ? (mask + (size_t)b * T * S) : nullptr;

    for (int t = wave; t < T; t += 4) {
        u16* qrow = Q + (size_t)(b * T + t) * ldq + h * DK_SZ;
        float qreg = b2f(qrow[lane]);
        int s1 = lane + 64, s2 = lane + 128, s3 = lane + 192;
        int c1 = (s1 < S) ? s1 : 0, c2 = (s2 < S) ? s2 : 0, c3 = (s3 < S) ? s3 : 0;
        float a0 = 0.f, a1 = 0.f, a2 = 0.f, a3 = 0.f;
        #pragma unroll 8
        for (int k = 0; k < DK_SZ; ++k) {
            float qk = __shfl(qreg, k, 64);
            a0 += qk * b2f(Kt[k * SPAD + lane]);
            a1 += qk * b2f(Kt[k * SPAD + c1]);
            a2 += qk * b2f(Kt[k * SPAD + c2]);
            a3 += qk * b2f(Kt[k * SPAD + c3]);
        }
        const int* mrow = mbase ? (mbase + (size_t)t * S) : nullptr;
        bool v0 = (!causal || lane <= t);
        bool v1 = (s1 < S) && (!causal || s1 <= t);
        bool v2 = (s2 < S) && (!causal || s2 <= t);
        bool v3 = (s3 < S) && (!causal || s3 <= t);
        if (mrow) {
            if (v0) v0 = (mrow[lane] != 1);
            if (v1) v1 = (mrow[s1] != 1);
            if (v2) v2 = (mrow[s2] != 1);
            if (v3) v3 = (mrow[s3] != 1);
        }
        float f0 = v0 ? a0 * rscale : NEG_BIG;
        float f1 = v1 ? a1 * rscale : NEG_BIG;
        float f2 = v2 ? a2 * rscale : NEG_BIG;
        float f3 = v3 ? a3 * rscale : NEG_BIG;
        float mx = fmaxf(fmaxf(f0, f1), fmaxf(f2, f3));
        #pragma unroll
        for (int off = 1; off < 64; off <<= 1)
            mx = fmaxf(mx, __shfl_xor(mx, off, 64));
        float p0 = __expf(f0 - mx);
        float p1 = __expf(f1 - mx);
        float p2 = __expf(f2 - mx);
        float p3 = __expf(f3 - mx);
        ps[wave][lane] = p0;
        if (s1 < S) ps[wave][s1] = p1;
        if (s2 < S) ps[wave][s2] = p2;
        if (s3 < S) ps[wave][s3] = p3;
        float sum = p0 + p1 + p2 + p3;
        #pragma unroll
        for (int off = 1; off < 64; off <<= 1)
            sum += __shfl_xor(sum, off, 64);
        float rden = (sum > 0.f) ? 1.0f / sum : 0.f;
        float pacc = 0.f;
        #pragma unroll 8
        for (int s = 0; s < S; ++s)
            pacc += ps[wave][s] * b2f(Vl[s * DK_SZ + lane]);
        qrow[lane] = f2b(pacc * rden);
    }
}

// ---------------- final logits: [rows,512](f32) @ ll_w[30,512]^T + b -> f32 ------
__global__ __launch_bounds__(256)
void logits_kernel(const float* __restrict__ X, const float* __restrict__ Wl,
                   const float* __restrict__ bl, float* __restrict__ out, int rows) {
    int idx = blockIdx.x * 256 + threadIdx.x;
    if (idx >= rows * V_SZ) return;
    int row = idx / V_SZ, v = idx % V_SZ;
    const float* xr = X + (size_t)row * D_MODEL;
    const float* wr = Wl + (size_t)v * D_MODEL;
    float acc = bl[v];
    #pragma unroll 8
    for (int k = 0; k < D_MODEL; ++k) acc += xr[k] * wr[k];
    out[idx] = acc;
}

extern "C" void kernel_launch(void* const* d_in, const int* in_sizes, int n_in,
                              void* d_out, int out_size, void* d_ws, size_t ws_size,
                              hipStream_t stream) {
    const float* x          = (const float*)d_in[0];
    const float* y          = (const float*)d_in[1];
    const int*   x_mask     = (const int*)d_in[2];
    const int*   y_mask     = (const int*)d_in[3];
    const float* enc_qkv    = (const float*)d_in[4];
    const float* enc_proj_w = (const float*)d_in[5];
    const float* enc_proj_b = (const float*)d_in[6];
    const float* enc_ln1_g  = (const float*)d_in[7];
    const float* enc_ln1_b  = (const float*)d_in[8];
    const float* enc_ff_w1  = (const float*)d_in[9];
    const float* enc_ff_b1  = (const float*)d_in[10];
    const float* enc_ff_w2  = (const float*)d_in[11];
    const float* enc_ff_b2  = (const float*)d_in[12];
    const float* enc_ln2_g  = (const float*)d_in[13];
    const float* enc_ln2_b  = (const float*)d_in[14];
    const float* dec_sa_qkv    = (const float*)d_in[15];
    const float* dec_sa_proj_w = (const float*)d_in[16];
    const float* dec_sa_proj_b = (const float*)d_in[17];
    const float* dec_ln1_g  = (const float*)d_in[18];
    const float* dec_ln1_b  = (const float*)d_in[19];
    const float* dec_ca_qkv    = (const float*)d_in[20];
    const float* dec_ca_proj_w = (const float*)d_in[21];
    const float* dec_ca_proj_b = (const float*)d_in[22];
    const float* dec_ln2_g  = (const float*)d_in[23];
    const float* dec_ln2_b  = (const float*)d_in[24];
    const float* dec_ff_w1  = (const float*)d_in[25];
    const float* dec_ff_b1  = (const float*)d_in[26];
    const float* dec_ff_w2  = (const float*)d_in[27];
    const float* dec_ff_b2  = (const float*)d_in[28];
    const float* dec_ln3_g  = (const float*)d_in[29];
    const float* dec_ln3_b  = (const float*)d_in[30];
    const float* ll_w       = (const float*)d_in[31];
    const float* ll_b       = (const float*)d_in[32];

    const int ME = B_SZ * TX_SZ;   // 12800
    const int MD = B_SZ * TY_SZ;   // 6400
    const float rscale = 1.0f / sqrtf((float)D_MODEL);

    // ---- workspace (bytes, 64-aligned) — total ~142 MB ----
    char* base = (char*)d_ws;
    size_t off = 0;
    auto alloc = [&](size_t bytes) {
        void* p = base + off;
        off = (off + bytes + 63) & ~(size_t)63;
        return p;
    };
    float* A_enc = (float*)alloc((size_t)ME * D_MODEL * 4);
    float* A_dec = (float*)alloc((size_t)MD * D_MODEL * 4);
    float* N1f   = (float*)alloc((size_t)ME * D_MODEL * 4);
    u16*   N1b   = (u16*)  alloc((size_t)ME * D_MODEL * 2);
    u16*   NQb   = (u16*)  alloc((size_t)MD * D_MODEL * 2);
    u16*   BIG   = (u16*)  alloc((size_t)ME * DFF_SZ * 2);
    u16*   Wa    = (u16*)  alloc((size_t)DFF_SZ * D_MODEL * 2);
    u16*   Wb2   = (u16*)  alloc((size_t)DFF_SZ * D_MODEL * 2);
    u16* QKVb = BIG;                        // [M,1536]
    u16* Hb   = BIG;                        // [M,2048]
    u16* KVb  = BIG;                        // [ME,1024]
    u16* Qca  = BIG + (size_t)ME * 1024;    // [MD,512]

    auto castw = [&](const float* in, u16* out, int n) {
        int n4 = n / 4;
        hipLaunchKernelGGL(castw_kernel, dim3((n4 + 255) / 256), dim3(256), 0, stream, in, out, n4);
    };
    auto ln = [&](const float* in, const float* g, const float* b,
                  float* outf, u16* outb, int rows) {
        hipLaunchKernelGGL(ln_kernel, dim3(rows), dim3(256), 0, stream, in, g, b, outf, outb, rows);
    };
    auto gemm = [&](const u16* A, int lda, const u16* W, int ldw, int M, int N, int K,
                    float* outf, int ldcf, u16* outb, int ldcb,
                    const float* bias, const float* resid, int ldr, int relu) {
        dim3 grid(N / 128, M / 128);
        hipLaunchKernelGGL(gemm_mfma, grid, dim3(256), 0, stream,
                           A, lda, W, ldw, outf, ldcf, outb, ldcb, bias, resid, ldr, relu, K);
    };
    auto attn = [&](u16* Q, int ldq, const u16* K, int ldk, const u16* V, int ldv,
                    const int* mask, int T, int S, int causal) {
        hipLaunchKernelGGL(attn_kernel, dim3(B_SZ * H_SZ), dim3(256), 0, stream,
                           Q, ldq, K, ldk, V, ldv, mask, T, S, causal, rscale);
    };

    const int WQKV = 3 * D_MODEL * D_MODEL;   // 786432
    const int WDD  = D_MODEL * D_MODEL;       // 262144
    const int WFF  = DFF_SZ * D_MODEL;        // 1048576

    // ---------------- encoder ----------------
    for (int l = 0; l < L_SZ; ++l) {
        const float* src = (l == 0) ? x : A_enc;
        castw(enc_qkv + (size_t)l * WQKV, Wa, WQKV);
        ln(src, enc_ln1_g + l * D_MODEL, enc_ln1_b + l * D_MODEL, N1f, N1b, ME);
        gemm(N1b, 512, Wa, 512, ME, 1536, 512, nullptr, 0, QKVb, 1536, nullptr, nullptr, 0, 0);
        attn(QKVb, 1536, QKVb + 512, 1536, QKVb + 1024, 1536, x_mask, TX_SZ, TX_SZ, 0);
        castw(enc_proj_w + (size_t)l * WDD, Wa, WDD);
        gemm(QKVb, 1536, Wa, 512, ME, 512, 512, A_enc, 512, nullptr, 0,
             enc_proj_b + l * D_MODEL, N1f, 512, 0);
        // FF
        ln(A_enc, enc_ln2_g + l * D_MODEL, enc_ln2_b + l * D_MODEL, nullptr, N1b, ME);
        castw(enc_ff_w1 + (size_t)l * WFF, Wa, WFF);
        gemm(N1b, 512, Wa, 512, ME, 2048, 512, nullptr, 0, Hb, 2048,
             enc_ff_b1 + l * DFF_SZ, nullptr, 0, 1);
        castw(enc_ff_w2 + (size_t)l * WFF, Wb2, WFF);
        gemm(Hb, 2048, Wb2, 2048, ME, 512, 2048, A_enc, 512, nullptr, 0,
             enc_ff_b2 + l * D_MODEL, A_enc, 512, 0);
    }

    // ---------------- decoder ----------------
    for (int l = 0; l < L_SZ; ++l) {
        const float* src = (l == 0) ? y : A_dec;
        castw(dec_sa_qkv + (size_t)l * WQKV, Wa, WQKV);
        ln(src, dec_ln1_g + l * D_MODEL, dec_ln1_b + l * D_MODEL, N1f, N1b, MD);
        gemm(N1b, 512, Wa, 512, MD, 1536, 512, nullptr, 0, QKVb, 1536, nullptr, nullptr, 0, 0);
        attn(QKVb, 1536, QKVb + 512, 1536, QKVb + 1024, 1536, y_mask, TY_SZ, TY_SZ, 1);
        castw(dec_sa_proj_w + (size_t)l * WDD, Wa, WDD);
        gemm(QKVb, 1536, Wa, 512, MD, 512, 512, A_dec, 512, nullptr, 0,
             dec_sa_proj_b + l * D_MODEL, N1f, 512, 0);
        // cross-attention
        ln(A_enc, dec_ln2_g + l * D_MODEL, dec_ln2_b + l * D_MODEL, nullptr, N1b, ME);
        ln(A_dec, dec_ln2_g + l * D_MODEL, dec_ln2_b + l * D_MODEL, N1f, NQb, MD);
        castw(dec_ca_qkv + (size_t)l * WQKV, Wa, WDD);           // Q weights
        gemm(NQb, 512, Wa, 512, MD, 512, 512, nullptr, 0, Qca, 512, nullptr, nullptr, 0, 0);
        castw(dec_ca_qkv + (size_t)l * WQKV + WDD, Wa, 2 * WDD); // K,V weights
        gemm(N1b, 512, Wa, 512, ME, 1024, 512, nullptr, 0, KVb, 1024, nullptr, nullptr, 0, 0);
        attn(Qca, 512, KVb, 1024, KVb + 512, 1024, nullptr, TY_SZ, TX_SZ, 0);
        castw(dec_ca_proj_w + (size_t)l * WDD, Wa, WDD);
        gemm(Qca, 512, Wa, 512, MD, 512, 512, A_dec, 512, nullptr, 0,
             dec_ca_proj_b + l * D_MODEL, N1f, 512, 0);
        // FF
        ln(A_dec, dec_ln3_g + l * D_MODEL, dec_ln3_b + l * D_MODEL, nullptr, N1b, MD);
        castw(dec_ff_w1 + (size_t)l * WFF, Wa, WFF);
        gemm(N1b, 512, Wa, 512, MD, 2048, 512, nullptr, 0, Hb, 2048,
             dec_ff_b1 + l * DFF_SZ, nullptr, 0, 1);
        castw(dec_ff_w2 + (size_t)l * WFF, Wb2, WFF);
        gemm(Hb, 2048, Wb2, 2048, MD, 512, 2048, A_dec, 512, nullptr, 0,
             dec_ff_b2 + l * D_MODEL, A_dec, 512, 0);
    }

    // ---------------- final projection ----------------
    {
        int total = MD * V_SZ;
        hipLaunchKernelGGL(logits_kernel, dim3((total + 255) / 256), dim3(256), 0, stream,
                           A_dec, ll_w, ll_b, (float*)d_out, MD);
    }
    (void)in_sizes; (void)n_in; (void)out_size; (void)ws_size;
}

// Round 5
// 3622.860 us; speedup vs baseline: 6.3682x; 1.6925x over previous
//
#include <hip/hip_runtime.h>
#include <math.h>

#define B_SZ   64
#define TX_SZ  200
#define TY_SZ  100
#define D_MODEL 512
#define H_SZ   8
#define DK_SZ  64
#define DFF_SZ 2048
#define L_SZ   4
#define V_SZ   30

#define NEG_BIG -1.0e30f

// attention LDS geometry (u16 units)
#define KSTR  72      /* K row stride: 144B, 16B-aligned */
#define VSTR  208     /* V^T row stride: 416B, 16B-aligned */
#define PSTR  200     /* P row stride: 400B, 16B-aligned */
#define KOFF  0
#define VOFF  (200 * KSTR)                 /* 14400 */
#define POFF  (VOFF + 64 * VSTR)           /* 27712 */
#define SMEMU (POFF + 4 * 16 * PSTR)       /* 40512 u16 = 81024 B -> 2 blocks/CU */

typedef unsigned short u16;
typedef __attribute__((ext_vector_type(8))) short short8;
typedef __attribute__((ext_vector_type(4))) float f32x4;
typedef __attribute__((ext_vector_type(4))) unsigned short u16x4;

__device__ __forceinline__ float b2f(u16 h) {
    union { unsigned int u; float f; } v; v.u = ((unsigned int)h) << 16; return v.f;
}
__device__ __forceinline__ u16 f2b(float f) {
    union { float f; unsigned int u; } v; v.f = f;
    unsigned int r = v.u + 0x7fffu + ((v.u >> 16) & 1u);
    return (u16)(r >> 16);
}

#define GLD16(gp, lp) __builtin_amdgcn_global_load_lds( \
    (const __attribute__((address_space(1))) unsigned int*)(gp), \
    (__attribute__((address_space(3))) unsigned int*)(lp), 16, 0, 0)

// ---------------- cast f32 -> bf16, 4 elems/thread ----------------
__global__ __launch_bounds__(256)
void castw_kernel(const float* __restrict__ in, u16* __restrict__ out, int n4) {
    int i = blockIdx.x * 256 + threadIdx.x;
    if (i < n4) {
        f32x4 v = ((const f32x4*)in)[i];
        u16x4 o;
        o.x = f2b(v.x); o.y = f2b(v.y); o.z = f2b(v.z); o.w = f2b(v.w);
        ((u16x4*)out)[i] = o;
    }
}

// ---------------- LayerNorm (rows x 512), dual f32/bf16 output ----------------
__global__ __launch_bounds__(256)
void ln_kernel(const float* __restrict__ in, const float* __restrict__ g,
               const float* __restrict__ b, float* outf, u16* outb, int rows) {
    int row = blockIdx.x;
    if (row >= rows) return;
    const float* xr = in + (size_t)row * D_MODEL;
    float s = 0.f, ss = 0.f;
    for (int i = threadIdx.x; i < D_MODEL; i += 256) {
        float v = xr[i];
        s += v; ss += v * v;
    }
    __shared__ float rs[256], rss[256];
    int tid = threadIdx.x;
    rs[tid] = s; rss[tid] = ss;
    __syncthreads();
    for (int w = 128; w > 0; w >>= 1) {
        if (tid < w) { rs[tid] += rs[tid + w]; rss[tid] += rss[tid + w]; }
        __syncthreads();
    }
    float mean = rs[0] * (1.0f / D_MODEL);
    float var  = rss[0] * (1.0f / D_MODEL) - mean * mean;
    float rstd = rsqrtf(var + 1e-5f);
    for (int i = tid; i < D_MODEL; i += 256) {
        float o = (xr[i] - mean) * rstd * g[i] + b[i];
        if (outf) outf[(size_t)row * D_MODEL + i] = o;
        if (outb) outb[(size_t)row * D_MODEL + i] = f2b(o);
    }
}

// ---------------- MFMA GEMM: C[M,N] = A[M,K](bf16) @ W[N,K](bf16)^T ------------
__global__ __launch_bounds__(256)
void gemm_mfma(const u16* __restrict__ A, int lda,
               const u16* __restrict__ W, int ldw,
               float* outf, int ldcf, u16* outb, int ldcb,
               const float* __restrict__ bias,
               const float* __restrict__ resid, int ldr,
               int relu, int K) {
    __shared__ u16 Alds[128 * 32];
    __shared__ u16 Blds[128 * 32];
    const int tid  = threadIdx.x;
    const int wave = tid >> 6, lane = tid & 63;
    const int lr = lane & 15, lq = lane >> 4;
    const int wm = (wave >> 1) * 64, wn = (wave & 1) * 64;
    const int m0 = blockIdx.y * 128, n0 = blockIdx.x * 128;
    const int grow = tid >> 2;
    const int gcol = (tid & 3) * 8;
    const int woff = wave * 512;

    f32x4 zero = {0.f, 0.f, 0.f, 0.f};
    f32x4 acc[4][4];
    #pragma unroll
    for (int i = 0; i < 4; ++i)
        #pragma unroll
        for (int j = 0; j < 4; ++j) acc[i][j] = zero;

    const u16* Ag = A + (size_t)m0 * lda;
    const u16* Wg = W + (size_t)n0 * ldw;

    for (int k0 = 0; k0 < K; k0 += 32) {
        GLD16(Ag + (size_t)grow * lda + k0 + gcol,        &Alds[woff]);
        GLD16(Ag + (size_t)(64 + grow) * lda + k0 + gcol, &Alds[2048 + woff]);
        GLD16(Wg + (size_t)grow * ldw + k0 + gcol,        &Blds[woff]);
        GLD16(Wg + (size_t)(64 + grow) * ldw + k0 + gcol, &Blds[2048 + woff]);
        __syncthreads();
        short8 af[4], bfr[4];
        #pragma unroll
        for (int i = 0; i < 4; ++i)
            af[i] = *(const short8*)&Alds[(wm + i * 16 + lr) * 32 + lq * 8];
        #pragma unroll
        for (int j = 0; j < 4; ++j)
            bfr[j] = *(const short8*)&Blds[(wn + j * 16 + lr) * 32 + lq * 8];
        #pragma unroll
        for (int i = 0; i < 4; ++i)
            #pragma unroll
            for (int j = 0; j < 4; ++j)
                acc[i][j] = __builtin_amdgcn_mfma_f32_16x16x32_bf16(af[i], bfr[j], acc[i][j], 0, 0, 0);
        __syncthreads();
    }

    #pragma unroll
    for (int i = 0; i < 4; ++i) {
        #pragma unroll
        for (int r = 0; r < 4; ++r) {
            int m = m0 + wm + i * 16 + lq * 4 + r;
            #pragma unroll
            for (int j = 0; j < 4; ++j) {
                int n = n0 + wn + j * 16 + lr;
                float c = acc[i][j][r];
                if (bias)  c += bias[n];
                if (resid) c += resid[(size_t)m * ldr + n];
                if (relu)  c = fmaxf(c, 0.f);
                if (outf) outf[(size_t)m * ldcf + n] = c;
                if (outb) outb[(size_t)m * ldcb + n] = f2b(c);
            }
        }
    }
}

// ---------------- attention v4: MFMA flash, block per (b,h), wave per q-tile ----
// K[S][64] and V^T[64][S] staged in LDS once; P per-wave region (no barriers
// after staging). O written in-place into the Q slice this block owns.
__global__ __launch_bounds__(256)
void attn_kernel(u16* __restrict__ Q, int ldq, const u16* __restrict__ K, int ldk,
                 const u16* __restrict__ V, int ldv,
                 const int* __restrict__ mask, int T, int S, int causal, float rscale) {
    __shared__ u16 smem[SMEMU];
    u16* Kl = smem + KOFF;
    u16* Vt = smem + VOFF;
    u16* Pl = smem + POFF;

    const int bh = blockIdx.x;
    const int h = bh % H_SZ, b = bh / H_SZ;
    const int tid = threadIdx.x, wave = tid >> 6, lane = tid & 63;
    const int lm = lane & 15, quad = lane >> 4;

    const u16* Kg = K + (size_t)(b * S) * ldk + h * DK_SZ;
    const u16* Vg = V + (size_t)(b * S) * ldv + h * DK_SZ;
    u16* Qg = Q + (size_t)(b * T) * ldq + h * DK_SZ;

    const int stiles = (S + 15) >> 4;
    const int Scols = stiles << 4;
    const int Pcap = (Scols < PSTR) ? Scols : PSTR;

    // stage K and V^T (coalesced global reads)
    for (int i = tid; i < S * DK_SZ; i += 256) {
        int s = i >> 6, d = i & 63;
        Kl[s * KSTR + d] = Kg[(size_t)s * ldk + d];
        Vt[d * VSTR + s] = Vg[(size_t)s * ldv + d];
    }
    // zero-fill V^T columns S..Scols-1 (avoid 0*NaN in the PV tail)
    int pad = Scols - S;
    for (int i = tid; i < pad * DK_SZ; i += 256) {
        int d = i / pad, s = S + (i % pad);
        Vt[d * VSTR + s] = 0;
    }
    __syncthreads();

    const short8 zero8 = {0, 0, 0, 0, 0, 0, 0, 0};
    const f32x4 zerof = {0.f, 0.f, 0.f, 0.f};
    u16* Pw = Pl + wave * (16 * PSTR);

    for (int t0 = wave * 16; t0 < T; t0 += 64) {
        // Q A-fragments (global, 16B/lane)
        int qr = t0 + lm; if (qr >= T) qr = T - 1;
        const u16* qrow = Qg + (size_t)qr * ldq;
        short8 qa0 = *(const short8*)(qrow + quad * 8);
        short8 qa1 = *(const short8*)(qrow + 32 + quad * 8);

        // QK^T: scores[m=quad*4+r][s=lm+16*st]
        f32x4 sc[13];
        #pragma unroll
        for (int st = 0; st < 13; ++st) if (st < stiles) {
            int srow = st * 16 + lm; if (srow >= S) srow = S - 1;
            const u16* kp = Kl + srow * KSTR + quad * 8;
            short8 kb0 = *(const short8*)kp;
            short8 kb1 = *(const short8*)(kp + 32);
            f32x4 c = zerof;
            c = __builtin_amdgcn_mfma_f32_16x16x32_bf16(qa0, kb0, c, 0, 0, 0);
            c = __builtin_amdgcn_mfma_f32_16x16x32_bf16(qa1, kb1, c, 0, 0, 0);
            sc[st] = c;
        }

        // mask + scale + row max
        float mx[4] = {NEG_BIG, NEG_BIG, NEG_BIG, NEG_BIG};
        #pragma unroll
        for (int st = 0; st < 13; ++st) if (st < stiles) {
            int s = st * 16 + lm;
            int smi = (s < S) ? s : S - 1;
            #pragma unroll
            for (int r = 0; r < 4; ++r) {
                int t = t0 + quad * 4 + r;
                int tc = (t < T) ? t : T - 1;
                bool valid = (s < S) && (!causal || s <= t);
                if (valid && mask) valid = (mask[(size_t)(b * T + tc) * S + smi] != 1);
                float f = valid ? sc[st][r] * rscale : NEG_BIG;
                sc[st][r] = f;
                mx[r] = fmaxf(mx[r], f);
            }
        }
        #pragma unroll
        for (int r = 0; r < 4; ++r) {
            #pragma unroll
            for (int off = 1; off < 16; off <<= 1)
                mx[r] = fmaxf(mx[r], __shfl_xor(mx[r], off, 64));
        }

        // exp + sum + write P (bf16) to per-wave LDS
        float sum[4] = {0.f, 0.f, 0.f, 0.f};
        #pragma unroll
        for (int st = 0; st < 13; ++st) if (st < stiles) {
            int col = st * 16 + lm;
            #pragma unroll
            for (int r = 0; r < 4; ++r) {
                float p = __expf(sc[st][r] - mx[r]);
                sum[r] += p;
                if (col < PSTR) Pw[(quad * 4 + r) * PSTR + col] = f2b(p);
            }
        }
        float rden[4];
        #pragma unroll
        for (int r = 0; r < 4; ++r) {
            #pragma unroll
            for (int off = 1; off < 16; off <<= 1)
                sum[r] += __shfl_xor(sum[r], off, 64);
            rden[r] = (sum[r] > 0.f) ? 1.0f / sum[r] : 0.f;
        }

        // PV: O[m][d] = sum_s P[m][s] * Vt[d][s]
        f32x4 ov[4] = {zerof, zerof, zerof, zerof};
        for (int k0 = 0; k0 < Pcap; k0 += 32) {
            int nq = (Pcap - k0) >> 3;   // valid 8-col quads in this k-tile
            short8 pa = (quad < nq) ? *(const short8*)(Pw + lm * PSTR + k0 + quad * 8)
                                    : zero8;
            #pragma unroll
            for (int dt = 0; dt < 4; ++dt) {
                short8 vb = (quad < nq)
                    ? *(const short8*)(Vt + (dt * 16 + lm) * VSTR + k0 + quad * 8)
                    : zero8;
                ov[dt] = __builtin_amdgcn_mfma_f32_16x16x32_bf16(pa, vb, ov[dt], 0, 0, 0);
            }
        }

        // store O (in-place into Q slice)
        #pragma unroll
        for (int r = 0; r < 4; ++r) {
            int t = t0 + quad * 4 + r;
            if (t < T) {
                u16* orow = Qg + (size_t)t * ldq;
                #pragma unroll
                for (int dt = 0; dt < 4; ++dt)
                    orow[dt * 16 + lm] = f2b(ov[dt][r] * rden[r]);
            }
        }
    }
}

// ---------------- final logits: [rows,512](f32) @ ll_w[30,512]^T + b -> f32 ------
__global__ __launch_bounds__(256)
void logits_kernel(const float* __restrict__ X, const float* __restrict__ Wl,
                   const float* __restrict__ bl, float* __restrict__ out, int rows) {
    int idx = blockIdx.x * 256 + threadIdx.x;
    if (idx >= rows * V_SZ) return;
    int row = idx / V_SZ, v = idx % V_SZ;
    const float* xr = X + (size_t)row * D_MODEL;
    const float* wr = Wl + (size_t)v * D_MODEL;
    float acc = bl[v];
    #pragma unroll 8
    for (int k = 0; k < D_MODEL; ++k) acc += xr[k] * wr[k];
    out[idx] = acc;
}

extern "C" void kernel_launch(void* const* d_in, const int* in_sizes, int n_in,
                              void* d_out, int out_size, void* d_ws, size_t ws_size,
                              hipStream_t stream) {
    const float* x          = (const float*)d_in[0];
    const float* y          = (const float*)d_in[1];
    const int*   x_mask     = (const int*)d_in[2];
    const int*   y_mask     = (const int*)d_in[3];
    const float* enc_qkv    = (const float*)d_in[4];
    const float* enc_proj_w = (const float*)d_in[5];
    const float* enc_proj_b = (const float*)d_in[6];
    const float* enc_ln1_g  = (const float*)d_in[7];
    const float* enc_ln1_b  = (const float*)d_in[8];
    const float* enc_ff_w1  = (const float*)d_in[9];
    const float* enc_ff_b1  = (const float*)d_in[10];
    const float* enc_ff_w2  = (const float*)d_in[11];
    const float* enc_ff_b2  = (const float*)d_in[12];
    const float* enc_ln2_g  = (const float*)d_in[13];
    const float* enc_ln2_b  = (const float*)d_in[14];
    const float* dec_sa_qkv    = (const float*)d_in[15];
    const float* dec_sa_proj_w = (const float*)d_in[16];
    const float* dec_sa_proj_b = (const float*)d_in[17];
    const float* dec_ln1_g  = (const float*)d_in[18];
    const float* dec_ln1_b  = (const float*)d_in[19];
    const float* dec_ca_qkv    = (const float*)d_in[20];
    const float* dec_ca_proj_w = (const float*)d_in[21];
    const float* dec_ca_proj_b = (const float*)d_in[22];
    const float* dec_ln2_g  = (const float*)d_in[23];
    const float* dec_ln2_b  = (const float*)d_in[24];
    const float* dec_ff_w1  = (const float*)d_in[25];
    const float* dec_ff_b1  = (const float*)d_in[26];
    const float* dec_ff_w2  = (const float*)d_in[27];
    const float* dec_ff_b2  = (const float*)d_in[28];
    const float* dec_ln3_g  = (const float*)d_in[29];
    const float* dec_ln3_b  = (const float*)d_in[30];
    const float* ll_w       = (const float*)d_in[31];
    const float* ll_b       = (const float*)d_in[32];

    const int ME = B_SZ * TX_SZ;   // 12800
    const int MD = B_SZ * TY_SZ;   // 6400
    const float rscale = 1.0f / sqrtf((float)D_MODEL);

    // ---- workspace ----
    char* base = (char*)d_ws;
    size_t off = 0;
    auto alloc = [&](size_t bytes) {
        void* p = base + off;
        off = (off + bytes + 63) & ~(size_t)63;
        return p;
    };
    float* A_enc = (float*)alloc((size_t)ME * D_MODEL * 4);
    float* A_dec = (float*)alloc((size_t)MD * D_MODEL * 4);
    float* N1f   = (float*)alloc((size_t)ME * D_MODEL * 4);
    u16*   N1b   = (u16*)  alloc((size_t)ME * D_MODEL * 2);
    u16*   NQb   = (u16*)  alloc((size_t)MD * D_MODEL * 2);
    u16*   BIG   = (u16*)  alloc((size_t)ME * DFF_SZ * 2);
    u16*   Wa    = (u16*)  alloc((size_t)DFF_SZ * D_MODEL * 2);
    u16*   Wb2   = (u16*)  alloc((size_t)DFF_SZ * D_MODEL * 2);
    u16* QKVb = BIG;                        // [M,1536]
    u16* Hb   = BIG;                        // [M,2048]
    u16* KVb  = BIG;                        // [ME,1024]
    u16* Qca  = BIG + (size_t)ME * 1024;    // [MD,512]

    auto castw = [&](const float* in, u16* out, int n) {
        int n4 = n / 4;
        hipLaunchKernelGGL(castw_kernel, dim3((n4 + 255) / 256), dim3(256), 0, stream, in, out, n4);
    };
    auto ln = [&](const float* in, const float* g, const float* b,
                  float* outf, u16* outb, int rows) {
        hipLaunchKernelGGL(ln_kernel, dim3(rows), dim3(256), 0, stream, in, g, b, outf, outb, rows);
    };
    auto gemm = [&](const u16* A, int lda, const u16* W, int ldw, int M, int N, int K,
                    float* outf, int ldcf, u16* outb, int ldcb,
                    const float* bias, const float* resid, int ldr, int relu) {
        dim3 grid(N / 128, M / 128);
        hipLaunchKernelGGL(gemm_mfma, grid, dim3(256), 0, stream,
                           A, lda, W, ldw, outf, ldcf, outb, ldcb, bias, resid, ldr, relu, K);
    };
    auto attn = [&](u16* Q, int ldq, const u16* K, int ldk, const u16* V, int ldv,
                    const int* mask, int T, int S, int causal) {
        hipLaunchKernelGGL(attn_kernel, dim3(B_SZ * H_SZ), dim3(256), 0, stream,
                           Q, ldq, K, ldk, V, ldv, mask, T, S, causal, rscale);
    };

    const int WQKV = 3 * D_MODEL * D_MODEL;
    const int WDD  = D_MODEL * D_MODEL;
    const int WFF  = DFF_SZ * D_MODEL;

    // ---------------- encoder ----------------
    for (int l = 0; l < L_SZ; ++l) {
        const float* src = (l == 0) ? x : A_enc;
        castw(enc_qkv + (size_t)l * WQKV, Wa, WQKV);
        ln(src, enc_ln1_g + l * D_MODEL, enc_ln1_b + l * D_MODEL, N1f, N1b, ME);
        gemm(N1b, 512, Wa, 512, ME, 1536, 512, nullptr, 0, QKVb, 1536, nullptr, nullptr, 0, 0);
        attn(QKVb, 1536, QKVb + 512, 1536, QKVb + 1024, 1536, x_mask, TX_SZ, TX_SZ, 0);
        castw(enc_proj_w + (size_t)l * WDD, Wa, WDD);
        gemm(QKVb, 1536, Wa, 512, ME, 512, 512, A_enc, 512, nullptr, 0,
             enc_proj_b + l * D_MODEL, N1f, 512, 0);
        ln(A_enc, enc_ln2_g + l * D_MODEL, enc_ln2_b + l * D_MODEL, nullptr, N1b, ME);
        castw(enc_ff_w1 + (size_t)l * WFF, Wa, WFF);
        gemm(N1b, 512, Wa, 512, ME, 2048, 512, nullptr, 0, Hb, 2048,
             enc_ff_b1 + l * DFF_SZ, nullptr, 0, 1);
        castw(enc_ff_w2 + (size_t)l * WFF, Wb2, WFF);
        gemm(Hb, 2048, Wb2, 2048, ME, 512, 2048, A_enc, 512, nullptr, 0,
             enc_ff_b2 + l * D_MODEL, A_enc, 512, 0);
    }

    // ---------------- decoder ----------------
    for (int l = 0; l < L_SZ; ++l) {
        const float* src = (l == 0) ? y : A_dec;
        castw(dec_sa_qkv + (size_t)l * WQKV, Wa, WQKV);
        ln(src, dec_ln1_g + l * D_MODEL, dec_ln1_b + l * D_MODEL, N1f, N1b, MD);
        gemm(N1b, 512, Wa, 512, MD, 1536, 512, nullptr, 0, QKVb, 1536, nullptr, nullptr, 0, 0);
        attn(QKVb, 1536, QKVb + 512, 1536, QKVb + 1024, 1536, y_mask, TY_SZ, TY_SZ, 1);
        castw(dec_sa_proj_w + (size_t)l * WDD, Wa, WDD);
        gemm(QKVb, 1536, Wa, 512, MD, 512, 512, A_dec, 512, nullptr, 0,
             dec_sa_proj_b + l * D_MODEL, N1f, 512, 0);
        // cross-attention
        ln(A_enc, dec_ln2_g + l * D_MODEL, dec_ln2_b + l * D_MODEL, nullptr, N1b, ME);
        ln(A_dec, dec_ln2_g + l * D_MODEL, dec_ln2_b + l * D_MODEL, N1f, NQb, MD);
        castw(dec_ca_qkv + (size_t)l * WQKV, Wa, WDD);           // Q weights
        gemm(NQb, 512, Wa, 512, MD, 512, 512, nullptr, 0, Qca, 512, nullptr, nullptr, 0, 0);
        castw(dec_ca_qkv + (size_t)l * WQKV + WDD, Wa, 2 * WDD); // K,V weights
        gemm(N1b, 512, Wa, 512, ME, 1024, 512, nullptr, 0, KVb, 1024, nullptr, nullptr, 0, 0);
        attn(Qca, 512, KVb, 1024, KVb + 512, 1024, nullptr, TY_SZ, TX_SZ, 0);
        castw(dec_ca_proj_w + (size_t)l * WDD, Wa, WDD);
        gemm(Qca, 512, Wa, 512, MD, 512, 512, A_dec, 512, nullptr, 0,
             dec_ca_proj_b + l * D_MODEL, N1f, 512, 0);
        // FF
        ln(A_dec, dec_ln3_g + l * D_MODEL, dec_ln3_b + l * D_MODEL, nullptr, N1b, MD);
        castw(dec_ff_w1 + (size_t)l * WFF, Wa, WFF);
        gemm(N1b, 512, Wa, 512, MD, 2048, 512, nullptr, 0, Hb, 2048,
             dec_ff_b1 + l * DFF_SZ, nullptr, 0, 1);
        castw(dec_ff_w2 + (size_t)l * WFF, Wb2, WFF);
        gemm(Hb, 2048, Wb2, 2048, MD, 512, 2048, A_dec, 512, nullptr, 0,
             dec_ff_b2 + l * D_MODEL, A_dec, 512, 0);
    }

    // ---------------- final projection ----------------
    {
        int total = MD * V_SZ;
        hipLaunchKernelGGL(logits_kernel, dim3((total + 255) / 256), dim3(256), 0, stream,
                           A_dec, ll_w, ll_b, (float*)d_out, MD);
    }
    (void)in_sizes; (void)n_in; (void)out_size; (void)ws_size;
}

// Round 6
// 3449.389 us; speedup vs baseline: 6.6885x; 1.0503x over previous
//
#include <hip/hip_runtime.h>
#include <math.h>

#define B_SZ   64
#define TX_SZ  200
#define TY_SZ  100
#define D_MODEL 512
#define H_SZ   8
#define DK_SZ  64
#define DFF_SZ 2048
#define L_SZ   4
#define V_SZ   30

#define NEG_BIG -1.0e30f

// attention LDS geometry (u16 units). All strides ≡ 0 mod 4 (8B-aligned rows)
// with (stride/2) mod 32 of gcd ≤ 2 with 32 → ≤2-way bank conflicts (free, m136).
#define KSTR  68      /* K row stride */
#define VSTR  212     /* V^T row stride */
#define PSTR  204     /* P row stride (>= 200 valid cols) */
#define KOFF  0
#define VOFF  (200 * KSTR)                 /* 13600 */
#define POFF  (VOFF + 64 * VSTR)           /* 27168 */
#define SMEMU (POFF + 8 * 16 * PSTR)       /* 53280 u16 = 106560 B -> 1 block/CU, 8 waves */

typedef unsigned short u16;
typedef __attribute__((ext_vector_type(8))) short short8;
typedef __attribute__((ext_vector_type(4))) short short4t;
typedef __attribute__((ext_vector_type(4))) float f32x4;
typedef __attribute__((ext_vector_type(4))) unsigned short u16x4;

__device__ __forceinline__ float b2f(u16 h) {
    union { unsigned int u; float f; } v; v.u = ((unsigned int)h) << 16; return v.f;
}
__device__ __forceinline__ u16 f2b(float f) {
    union { float f; unsigned int u; } v; v.f = f;
    unsigned int r = v.u + 0x7fffu + ((v.u >> 16) & 1u);
    return (u16)(r >> 16);
}
// 16B LDS fragment load from an 8B-aligned address (2 x b64)
__device__ __forceinline__ short8 ld8(const u16* p) {
    short4t a = *(const short4t*)p;
    short4t b = *(const short4t*)(p + 4);
    return __builtin_shufflevector(a, b, 0, 1, 2, 3, 4, 5, 6, 7);
}

#define GLD16(gp, lp) __builtin_amdgcn_global_load_lds( \
    (const __attribute__((address_space(1))) unsigned int*)(gp), \
    (__attribute__((address_space(3))) unsigned int*)(lp), 16, 0, 0)

// ---------------- cast f32 -> bf16, 4 elems/thread ----------------
__global__ __launch_bounds__(256)
void castw_kernel(const float* __restrict__ in, u16* __restrict__ out, int n4) {
    int i = blockIdx.x * 256 + threadIdx.x;
    if (i < n4) {
        f32x4 v = ((const f32x4*)in)[i];
        u16x4 o;
        o.x = f2b(v.x); o.y = f2b(v.y); o.z = f2b(v.z); o.w = f2b(v.w);
        ((u16x4*)out)[i] = o;
    }
}

// ---------------- LayerNorm (rows x 512), dual f32/bf16 output ----------------
__global__ __launch_bounds__(256)
void ln_kernel(const float* __restrict__ in, const float* __restrict__ g,
               const float* __restrict__ b, float* outf, u16* outb, int rows) {
    int row = blockIdx.x;
    if (row >= rows) return;
    const float* xr = in + (size_t)row * D_MODEL;
    float s = 0.f, ss = 0.f;
    for (int i = threadIdx.x; i < D_MODEL; i += 256) {
        float v = xr[i];
        s += v; ss += v * v;
    }
    __shared__ float rs[256], rss[256];
    int tid = threadIdx.x;
    rs[tid] = s; rss[tid] = ss;
    __syncthreads();
    for (int w = 128; w > 0; w >>= 1) {
        if (tid < w) { rs[tid] += rs[tid + w]; rss[tid] += rss[tid + w]; }
        __syncthreads();
    }
    float mean = rs[0] * (1.0f / D_MODEL);
    float var  = rss[0] * (1.0f / D_MODEL) - mean * mean;
    float rstd = rsqrtf(var + 1e-5f);
    for (int i = tid; i < D_MODEL; i += 256) {
        float o = (xr[i] - mean) * rstd * g[i] + b[i];
        if (outf) outf[(size_t)row * D_MODEL + i] = o;
        if (outb) outb[(size_t)row * D_MODEL + i] = f2b(o);
    }
}

// ---------------- MFMA GEMM: C[M,N] = A[M,K](bf16) @ W[N,K](bf16)^T ------------
// BM=128 fixed, BN templated (128 or 64). BN=64 doubles block count for
// small-N dec GEMMs (M=6400,N=512: 200 -> 400 blocks, full CU coverage).
template<int BN>
__global__ __launch_bounds__(256)
void gemm_mfma_t(const u16* __restrict__ A, int lda,
                 const u16* __restrict__ W, int ldw,
                 float* outf, int ldcf, u16* outb, int ldcb,
                 const float* __restrict__ bias,
                 const float* __restrict__ resid, int ldr,
                 int relu, int K) {
    constexpr int NJ = BN / 32;           // j-tiles per wave
    __shared__ u16 Alds[128 * 32];
    __shared__ u16 Blds[BN * 32];
    const int tid  = threadIdx.x;
    const int wave = tid >> 6, lane = tid & 63;
    const int lr = lane & 15, lq = lane >> 4;
    const int wm = (wave >> 1) * 64, wn = (wave & 1) * (BN / 2);
    const int m0 = blockIdx.y * 128, n0 = blockIdx.x * BN;
    const int grow = tid >> 2;
    const int gcol = (tid & 3) * 8;
    const int woff = wave * 512;

    f32x4 zero = {0.f, 0.f, 0.f, 0.f};
    f32x4 acc[4][NJ];
    #pragma unroll
    for (int i = 0; i < 4; ++i)
        #pragma unroll
        for (int j = 0; j < NJ; ++j) acc[i][j] = zero;

    const u16* Ag = A + (size_t)m0 * lda;
    const u16* Wg = W + (size_t)n0 * ldw;

    for (int k0 = 0; k0 < K; k0 += 32) {
        GLD16(Ag + (size_t)grow * lda + k0 + gcol,        &Alds[woff]);
        GLD16(Ag + (size_t)(64 + grow) * lda + k0 + gcol, &Alds[2048 + woff]);
        GLD16(Wg + (size_t)grow * ldw + k0 + gcol,        &Blds[woff]);
        if (BN == 128)
            GLD16(Wg + (size_t)(64 + grow) * ldw + k0 + gcol, &Blds[2048 + woff]);
        __syncthreads();
        short8 af[4], bfr[NJ];
        #pragma unroll
        for (int i = 0; i < 4; ++i)
            af[i] = *(const short8*)&Alds[(wm + i * 16 + lr) * 32 + lq * 8];
        #pragma unroll
        for (int j = 0; j < NJ; ++j)
            bfr[j] = *(const short8*)&Blds[(wn + j * 16 + lr) * 32 + lq * 8];
        #pragma unroll
        for (int i = 0; i < 4; ++i)
            #pragma unroll
            for (int j = 0; j < NJ; ++j)
                acc[i][j] = __builtin_amdgcn_mfma_f32_16x16x32_bf16(af[i], bfr[j], acc[i][j], 0, 0, 0);
        __syncthreads();
    }

    #pragma unroll
    for (int i = 0; i < 4; ++i) {
        #pragma unroll
        for (int r = 0; r < 4; ++r) {
            int m = m0 + wm + i * 16 + lq * 4 + r;
            #pragma unroll
            for (int j = 0; j < NJ; ++j) {
                int n = n0 + wn + j * 16 + lr;
                float c = acc[i][j][r];
                if (bias)  c += bias[n];
                if (resid) c += resid[(size_t)m * ldr + n];
                if (relu)  c = fmaxf(c, 0.f);
                if (outf) outf[(size_t)m * ldcf + n] = c;
                if (outb) outb[(size_t)m * ldcb + n] = f2b(c);
            }
        }
    }
}

// ---------------- attention v5: MFMA flash, block per (b,h), 8 waves ----------
// K[S][64] and V^T[64][S] staged once in LDS; per-wave P region (no barriers
// after staging). O written in-place into the Q slice this block owns.
__global__ __launch_bounds__(512)
void attn_kernel(u16* __restrict__ Q, int ldq, const u16* __restrict__ K, int ldk,
                 const u16* __restrict__ V, int ldv,
                 const int* __restrict__ mask, int T, int S, int causal, float rscale) {
    __shared__ u16 smem[SMEMU];
    u16* Kl = smem + KOFF;
    u16* Vt = smem + VOFF;
    u16* Pl = smem + POFF;

    const int bh = blockIdx.x;
    const int h = bh % H_SZ, b = bh / H_SZ;
    const int tid = threadIdx.x, wave = tid >> 6, lane = tid & 63;
    const int lm = lane & 15, quad = lane >> 4;

    const u16* Kg = K + (size_t)(b * S) * ldk + h * DK_SZ;
    const u16* Vg = V + (size_t)(b * S) * ldv + h * DK_SZ;
    u16* Qg = Q + (size_t)(b * T) * ldq + h * DK_SZ;

    const int stiles = (S + 15) >> 4;
    const int Scols = stiles << 4;
    const int Pcap = (Scols < PSTR) ? Scols : PSTR;

    // stage K and V^T (coalesced global; LDS writes <=2-way conflicts)
    for (int i = tid; i < S * DK_SZ; i += 512) {
        int s = i >> 6, d = i & 63;
        Kl[s * KSTR + d] = Kg[(size_t)s * ldk + d];
        Vt[d * VSTR + s] = Vg[(size_t)s * ldv + d];
    }
    int pad = Scols - S;
    for (int i = tid; i < pad * DK_SZ; i += 512) {
        int d = i / pad, s = S + (i % pad);
        Vt[d * VSTR + s] = 0;
    }
    __syncthreads();

    const short8 zero8 = {0, 0, 0, 0, 0, 0, 0, 0};
    const f32x4 zerof = {0.f, 0.f, 0.f, 0.f};
    u16* Pw = Pl + wave * (16 * PSTR);

    for (int t0 = wave * 16; t0 < T; t0 += 128) {
        // Q A-fragments (global, 16B-aligned)
        int qr = t0 + lm; if (qr >= T) qr = T - 1;
        const u16* qrow = Qg + (size_t)qr * ldq;
        short8 qa0 = *(const short8*)(qrow + quad * 8);
        short8 qa1 = *(const short8*)(qrow + 32 + quad * 8);

        // QK^T
        f32x4 sc[13];
        #pragma unroll
        for (int st = 0; st < 13; ++st) if (st < stiles) {
            int srow = st * 16 + lm; if (srow >= S) srow = S - 1;
            const u16* kp = Kl + srow * KSTR + quad * 8;
            short8 kb0 = ld8(kp);
            short8 kb1 = ld8(kp + 32);
            f32x4 c = zerof;
            c = __builtin_amdgcn_mfma_f32_16x16x32_bf16(qa0, kb0, c, 0, 0, 0);
            c = __builtin_amdgcn_mfma_f32_16x16x32_bf16(qa1, kb1, c, 0, 0, 0);
            sc[st] = c;
        }

        // mask + scale + row max
        float mx[4] = {NEG_BIG, NEG_BIG, NEG_BIG, NEG_BIG};
        #pragma unroll
        for (int st = 0; st < 13; ++st) if (st < stiles) {
            int s = st * 16 + lm;
            int smi = (s < S) ? s : S - 1;
            #pragma unroll
            for (int r = 0; r < 4; ++r) {
                int t = t0 + quad * 4 + r;
                int tc = (t < T) ? t : T - 1;
                bool valid = (s < S) && (!causal || s <= t);
                if (valid && mask) valid = (mask[(size_t)(b * T + tc) * S + smi] != 1);
                float f = valid ? sc[st][r] * rscale : NEG_BIG;
                sc[st][r] = f;
                mx[r] = fmaxf(mx[r], f);
            }
        }
        #pragma unroll
        for (int r = 0; r < 4; ++r) {
            #pragma unroll
            for (int off = 1; off < 16; off <<= 1)
                mx[r] = fmaxf(mx[r], __shfl_xor(mx[r], off, 64));
        }

        // exp + sum + write P (bf16) to per-wave LDS
        float sum[4] = {0.f, 0.f, 0.f, 0.f};
        #pragma unroll
        for (int st = 0; st < 13; ++st) if (st < stiles) {
            int col = st * 16 + lm;
            #pragma unroll
            for (int r = 0; r < 4; ++r) {
                float p = __expf(sc[st][r] - mx[r]);
                sum[r] += p;
                if (col < PSTR) Pw[(quad * 4 + r) * PSTR + col] = f2b(p);
            }
        }
        float rden[4];
        #pragma unroll
        for (int r = 0; r < 4; ++r) {
            #pragma unroll
            for (int off = 1; off < 16; off <<= 1)
                sum[r] += __shfl_xor(sum[r], off, 64);
            rden[r] = (sum[r] > 0.f) ? 1.0f / sum[r] : 0.f;
        }

        // PV: O[m][d] = sum_s P[m][s] * Vt[d][s]
        f32x4 ov[4] = {zerof, zerof, zerof, zerof};
        for (int k0 = 0; k0 < Pcap; k0 += 32) {
            int nq = (Pcap - k0) >> 3;
            short8 pa = (quad < nq) ? ld8(Pw + lm * PSTR + k0 + quad * 8) : zero8;
            #pragma unroll
            for (int dt = 0; dt < 4; ++dt) {
                short8 vb = (quad < nq)
                    ? ld8(Vt + (dt * 16 + lm) * VSTR + k0 + quad * 8)
                    : zero8;
                ov[dt] = __builtin_amdgcn_mfma_f32_16x16x32_bf16(pa, vb, ov[dt], 0, 0, 0);
            }
        }

        // store O (in-place into Q slice)
        #pragma unroll
        for (int r = 0; r < 4; ++r) {
            int t = t0 + quad * 4 + r;
            if (t < T) {
                u16* orow = Qg + (size_t)t * ldq;
                #pragma unroll
                for (int dt = 0; dt < 4; ++dt)
                    orow[dt * 16 + lm] = f2b(ov[dt][r] * rden[r]);
            }
        }
    }
}

// ---------------- final logits: [rows,512](f32) @ ll_w[30,512]^T + b -> f32 ------
__global__ __launch_bounds__(256)
void logits_kernel(const float* __restrict__ X, const float* __restrict__ Wl,
                   const float* __restrict__ bl, float* __restrict__ out, int rows) {
    int idx = blockIdx.x * 256 + threadIdx.x;
    if (idx >= rows * V_SZ) return;
    int row = idx / V_SZ, v = idx % V_SZ;
    const float* xr = X + (size_t)row * D_MODEL;
    const float* wr = Wl + (size_t)v * D_MODEL;
    float acc = bl[v];
    #pragma unroll 8
    for (int k = 0; k < D_MODEL; ++k) acc += xr[k] * wr[k];
    out[idx] = acc;
}

extern "C" void kernel_launch(void* const* d_in, const int* in_sizes, int n_in,
                              void* d_out, int out_size, void* d_ws, size_t ws_size,
                              hipStream_t stream) {
    const float* x          = (const float*)d_in[0];
    const float* y          = (const float*)d_in[1];
    const int*   x_mask     = (const int*)d_in[2];
    const int*   y_mask     = (const int*)d_in[3];
    const float* enc_qkv    = (const float*)d_in[4];
    const float* enc_proj_w = (const float*)d_in[5];
    const float* enc_proj_b = (const float*)d_in[6];
    const float* enc_ln1_g  = (const float*)d_in[7];
    const float* enc_ln1_b  = (const float*)d_in[8];
    const float* enc_ff_w1  = (const float*)d_in[9];
    const float* enc_ff_b1  = (const float*)d_in[10];
    const float* enc_ff_w2  = (const float*)d_in[11];
    const float* enc_ff_b2  = (const float*)d_in[12];
    const float* enc_ln2_g  = (const float*)d_in[13];
    const float* enc_ln2_b  = (const float*)d_in[14];
    const float* dec_sa_qkv    = (const float*)d_in[15];
    const float* dec_sa_proj_w = (const float*)d_in[16];
    const float* dec_sa_proj_b = (const float*)d_in[17];
    const float* dec_ln1_g  = (const float*)d_in[18];
    const float* dec_ln1_b  = (const float*)d_in[19];
    const float* dec_ca_qkv    = (const float*)d_in[20];
    const float* dec_ca_proj_w = (const float*)d_in[21];
    const float* dec_ca_proj_b = (const float*)d_in[22];
    const float* dec_ln2_g  = (const float*)d_in[23];
    const float* dec_ln2_b  = (const float*)d_in[24];
    const float* dec_ff_w1  = (const float*)d_in[25];
    const float* dec_ff_b1  = (const float*)d_in[26];
    const float* dec_ff_w2  = (const float*)d_in[27];
    const float* dec_ff_b2  = (const float*)d_in[28];
    const float* dec_ln3_g  = (const float*)d_in[29];
    const float* dec_ln3_b  = (const float*)d_in[30];
    const float* ll_w       = (const float*)d_in[31];
    const float* ll_b       = (const float*)d_in[32];

    const int ME = B_SZ * TX_SZ;   // 12800
    const int MD = B_SZ * TY_SZ;   // 6400
    const float rscale = 1.0f / sqrtf((float)D_MODEL);

    // ---- workspace ----
    char* base = (char*)d_ws;
    size_t off = 0;
    auto alloc = [&](size_t bytes) {
        void* p = base + off;
        off = (off + bytes + 63) & ~(size_t)63;
        return p;
    };
    float* A_enc = (float*)alloc((size_t)ME * D_MODEL * 4);
    float* A_dec = (float*)alloc((size_t)MD * D_MODEL * 4);
    float* N1f   = (float*)alloc((size_t)ME * D_MODEL * 4);
    u16*   N1b   = (u16*)  alloc((size_t)ME * D_MODEL * 2);
    u16*   NQb   = (u16*)  alloc((size_t)MD * D_MODEL * 2);
    u16*   BIG   = (u16*)  alloc((size_t)ME * DFF_SZ * 2);
    u16*   Wa    = (u16*)  alloc((size_t)DFF_SZ * D_MODEL * 2);
    u16*   Wb2   = (u16*)  alloc((size_t)DFF_SZ * D_MODEL * 2);
    u16* QKVb = BIG;                        // [M,1536]
    u16* Hb   = BIG;                        // [M,2048]
    u16* KVb  = BIG;                        // [ME,1024]
    u16* Qca  = BIG + (size_t)ME * 1024;    // [MD,512]

    auto castw = [&](const float* in, u16* out, int n) {
        int n4 = n / 4;
        hipLaunchKernelGGL(castw_kernel, dim3((n4 + 255) / 256), dim3(256), 0, stream, in, out, n4);
    };
    auto ln = [&](const float* in, const float* g, const float* b,
                  float* outf, u16* outb, int rows) {
        hipLaunchKernelGGL(ln_kernel, dim3(rows), dim3(256), 0, stream, in, g, b, outf, outb, rows);
    };
    auto gemm = [&](const u16* A, int lda, const u16* W, int ldw, int M, int N, int K,
                    float* outf, int ldcf, u16* outb, int ldcb,
                    const float* bias, const float* resid, int ldr, int relu) {
        int blocks128 = (M / 128) * (N / 128);
        if (blocks128 < 256) {
            dim3 grid(N / 64, M / 128);
            hipLaunchKernelGGL((gemm_mfma_t<64>), grid, dim3(256), 0, stream,
                               A, lda, W, ldw, outf, ldcf, outb, ldcb, bias, resid, ldr, relu, K);
        } else {
            dim3 grid(N / 128, M / 128);
            hipLaunchKernelGGL((gemm_mfma_t<128>), grid, dim3(256), 0, stream,
                               A, lda, W, ldw, outf, ldcf, outb, ldcb, bias, resid, ldr, relu, K);
        }
    };
    auto attn = [&](u16* Q, int ldq, const u16* K, int ldk, const u16* V, int ldv,
                    const int* mask, int T, int S, int causal) {
        hipLaunchKernelGGL(attn_kernel, dim3(B_SZ * H_SZ), dim3(512), 0, stream,
                           Q, ldq, K, ldk, V, ldv, mask, T, S, causal, rscale);
    };

    const int WQKV = 3 * D_MODEL * D_MODEL;
    const int WDD  = D_MODEL * D_MODEL;
    const int WFF  = DFF_SZ * D_MODEL;

    // ---------------- encoder ----------------
    for (int l = 0; l < L_SZ; ++l) {
        const float* src = (l == 0) ? x : A_enc;
        castw(enc_qkv + (size_t)l * WQKV, Wa, WQKV);
        ln(src, enc_ln1_g + l * D_MODEL, enc_ln1_b + l * D_MODEL, N1f, N1b, ME);
        gemm(N1b, 512, Wa, 512, ME, 1536, 512, nullptr, 0, QKVb, 1536, nullptr, nullptr, 0, 0);
        attn(QKVb, 1536, QKVb + 512, 1536, QKVb + 1024, 1536, x_mask, TX_SZ, TX_SZ, 0);
        castw(enc_proj_w + (size_t)l * WDD, Wa, WDD);
        gemm(QKVb, 1536, Wa, 512, ME, 512, 512, A_enc, 512, nullptr, 0,
             enc_proj_b + l * D_MODEL, N1f, 512, 0);
        ln(A_enc, enc_ln2_g + l * D_MODEL, enc_ln2_b + l * D_MODEL, nullptr, N1b, ME);
        castw(enc_ff_w1 + (size_t)l * WFF, Wa, WFF);
        gemm(N1b, 512, Wa, 512, ME, 2048, 512, nullptr, 0, Hb, 2048,
             enc_ff_b1 + l * DFF_SZ, nullptr, 0, 1);
        castw(enc_ff_w2 + (size_t)l * WFF, Wb2, WFF);
        gemm(Hb, 2048, Wb2, 2048, ME, 512, 2048, A_enc, 512, nullptr, 0,
             enc_ff_b2 + l * D_MODEL, A_enc, 512, 0);
    }

    // ---------------- decoder ----------------
    for (int l = 0; l < L_SZ; ++l) {
        const float* src = (l == 0) ? y : A_dec;
        castw(dec_sa_qkv + (size_t)l * WQKV, Wa, WQKV);
        ln(src, dec_ln1_g + l * D_MODEL, dec_ln1_b + l * D_MODEL, N1f, N1b, MD);
        gemm(N1b, 512, Wa, 512, MD, 1536, 512, nullptr, 0, QKVb, 1536, nullptr, nullptr, 0, 0);
        attn(QKVb, 1536, QKVb + 512, 1536, QKVb + 1024, 1536, y_mask, TY_SZ, TY_SZ, 1);
        castw(dec_sa_proj_w + (size_t)l * WDD, Wa, WDD);
        gemm(QKVb, 1536, Wa, 512, MD, 512, 512, A_dec, 512, nullptr, 0,
             dec_sa_proj_b + l * D_MODEL, N1f, 512, 0);
        // cross-attention
        ln(A_enc, dec_ln2_g + l * D_MODEL, dec_ln2_b + l * D_MODEL, nullptr, N1b, ME);
        ln(A_dec, dec_ln2_g + l * D_MODEL, dec_ln2_b + l * D_MODEL, N1f, NQb, MD);
        castw(dec_ca_qkv + (size_t)l * WQKV, Wa, WDD);           // Q weights
        gemm(NQb, 512, Wa, 512, MD, 512, 512, nullptr, 0, Qca, 512, nullptr, nullptr, 0, 0);
        castw(dec_ca_qkv + (size_t)l * WQKV + WDD, Wa, 2 * WDD); // K,V weights
        gemm(N1b, 512, Wa, 512, ME, 1024, 512, nullptr, 0, KVb, 1024, nullptr, nullptr, 0, 0);
        attn(Qca, 512, KVb, 1024, KVb + 512, 1024, nullptr, TY_SZ, TX_SZ, 0);
        castw(dec_ca_proj_w + (size_t)l * WDD, Wa, WDD);
        gemm(Qca, 512, Wa, 512, MD, 512, 512, A_dec, 512, nullptr, 0,
             dec_ca_proj_b + l * D_MODEL, N1f, 512, 0);
        // FF
        ln(A_dec, dec_ln3_g + l * D_MODEL, dec_ln3_b + l * D_MODEL, nullptr, N1b, MD);
        castw(dec_ff_w1 + (size_t)l * WFF, Wa, WFF);
        gemm(N1b, 512, Wa, 512, MD, 2048, 512, nullptr, 0, Hb, 2048,
             dec_ff_b1 + l * DFF_SZ, nullptr, 0, 1);
        castw(dec_ff_w2 + (size_t)l * WFF, Wb2, WFF);
        gemm(Hb, 2048, Wb2, 2048, MD, 512, 2048, A_dec, 512, nullptr, 0,
             dec_ff_b2 + l * D_MODEL, A_dec, 512, 0);
    }

    // ---------------- final projection ----------------
    {
        int total = MD * V_SZ;
        hipLaunchKernelGGL(logits_kernel, dim3((total + 255) / 256), dim3(256), 0, stream,
                           A_dec, ll_w, ll_b, (float*)d_out, MD);
    }
    (void)in_sizes; (void)n_in; (void)out_size; (void)ws_size;
}

// Round 7
// 3156.246 us; speedup vs baseline: 7.3097x; 1.0929x over previous
//
#include <hip/hip_runtime.h>
#include <math.h>

#define B_SZ   64
#define TX_SZ  200
#define TY_SZ  100
#define D_MODEL 512
#define H_SZ   8
#define DK_SZ  64
#define DFF_SZ 2048
#define L_SZ   4
#define V_SZ   30

#define NEG_BIG -1.0e30f

// attention LDS geometry (u16 units). Strides chosen so (stride/2) mod 32 has
// gcd ≤ 2 with 32 → ≤2-way bank conflicts (free, m136); rows 8B-aligned.
#define KSTR  68      /* K row stride */
#define VSTR  212     /* V^T row stride */
#define PSTR  204     /* P row stride (>= 200 valid cols) */
#define KOFF  0
#define VOFF  (200 * KSTR)                 /* 13600 */
#define POFF  (VOFF + 64 * VSTR)           /* 27168 */
#define SMEMU (POFF + 4 * 16 * PSTR)       /* 40224 u16 = 80448 B -> 2 blocks/CU */

typedef unsigned short u16;
typedef __attribute__((ext_vector_type(8))) short short8;
typedef __attribute__((ext_vector_type(4))) short short4t;
typedef __attribute__((ext_vector_type(4))) float f32x4;
typedef __attribute__((ext_vector_type(4))) unsigned short u16x4;

__device__ __forceinline__ float b2f(u16 h) {
    union { unsigned int u; float f; } v; v.u = ((unsigned int)h) << 16; return v.f;
}
__device__ __forceinline__ u16 f2b(float f) {
    union { float f; unsigned int u; } v; v.f = f;
    unsigned int r = v.u + 0x7fffu + ((v.u >> 16) & 1u);
    return (u16)(r >> 16);
}
// 16B LDS fragment load from an 8B-aligned address (2 x b64)
__device__ __forceinline__ short8 ld8(const u16* p) {
    short4t a = *(const short4t*)p;
    short4t b = *(const short4t*)(p + 4);
    return __builtin_shufflevector(a, b, 0, 1, 2, 3, 4, 5, 6, 7);
}

#define GLD16(gp, lp) __builtin_amdgcn_global_load_lds( \
    (const __attribute__((address_space(1))) unsigned int*)(gp), \
    (__attribute__((address_space(3))) unsigned int*)(lp), 16, 0, 0)

// ---------------- cast f32 -> bf16, 4 elems/thread ----------------
__global__ __launch_bounds__(256)
void castw_kernel(const float* __restrict__ in, u16* __restrict__ out, int n4) {
    int i = blockIdx.x * 256 + threadIdx.x;
    if (i < n4) {
        f32x4 v = ((const f32x4*)in)[i];
        u16x4 o;
        o.x = f2b(v.x); o.y = f2b(v.y); o.z = f2b(v.z); o.w = f2b(v.w);
        ((u16x4*)out)[i] = o;
    }
}

// ---------------- LayerNorm (rows x 512): wave per row, no barriers ----------
__global__ __launch_bounds__(256)
void ln_kernel(const float* __restrict__ in, const float* __restrict__ g,
               const float* __restrict__ b, float* outf, u16* outb, int rows) {
    int row = blockIdx.x * 4 + (threadIdx.x >> 6);
    int lane = threadIdx.x & 63;
    if (row >= rows) return;
    const f32x4* xr = (const f32x4*)(in + (size_t)row * D_MODEL);
    f32x4 v0 = xr[lane];
    f32x4 v1 = xr[lane + 64];
    float s  = v0.x + v0.y + v0.z + v0.w + v1.x + v1.y + v1.z + v1.w;
    float ss = v0.x*v0.x + v0.y*v0.y + v0.z*v0.z + v0.w*v0.w
             + v1.x*v1.x + v1.y*v1.y + v1.z*v1.z + v1.w*v1.w;
    #pragma unroll
    for (int off = 1; off < 64; off <<= 1) {
        s  += __shfl_xor(s, off, 64);
        ss += __shfl_xor(ss, off, 64);
    }
    float mean = s * (1.0f / D_MODEL);
    float var  = ss * (1.0f / D_MODEL) - mean * mean;
    float rstd = rsqrtf(var + 1e-5f);
    f32x4 g0 = ((const f32x4*)g)[lane],      g1 = ((const f32x4*)g)[lane + 64];
    f32x4 b0 = ((const f32x4*)b)[lane],      b1 = ((const f32x4*)b)[lane + 64];
    f32x4 o0, o1;
    o0.x = (v0.x - mean) * rstd * g0.x + b0.x;
    o0.y = (v0.y - mean) * rstd * g0.y + b0.y;
    o0.z = (v0.z - mean) * rstd * g0.z + b0.z;
    o0.w = (v0.w - mean) * rstd * g0.w + b0.w;
    o1.x = (v1.x - mean) * rstd * g1.x + b1.x;
    o1.y = (v1.y - mean) * rstd * g1.y + b1.y;
    o1.z = (v1.z - mean) * rstd * g1.z + b1.z;
    o1.w = (v1.w - mean) * rstd * g1.w + b1.w;
    if (outf) {
        f32x4* of = (f32x4*)(outf + (size_t)row * D_MODEL);
        of[lane] = o0; of[lane + 64] = o1;
    }
    if (outb) {
        u16x4* ob = (u16x4*)(outb + (size_t)row * D_MODEL);
        u16x4 p0, p1;
        p0.x = f2b(o0.x); p0.y = f2b(o0.y); p0.z = f2b(o0.z); p0.w = f2b(o0.w);
        p1.x = f2b(o1.x); p1.y = f2b(o1.y); p1.z = f2b(o1.z); p1.w = f2b(o1.w);
        ob[lane] = p0; ob[lane + 64] = p1;
    }
}

// ---------------- MFMA GEMM: C[M,N] = A[M,K](bf16) @ W[N,K](bf16)^T ------------
template<int BN>
__global__ __launch_bounds__(256)
void gemm_mfma_t(const u16* __restrict__ A, int lda,
                 const u16* __restrict__ W, int ldw,
                 float* outf, int ldcf, u16* outb, int ldcb,
                 const float* __restrict__ bias,
                 const float* __restrict__ resid, int ldr,
                 int relu, int K) {
    constexpr int NJ = BN / 32;
    __shared__ u16 Alds[128 * 32];
    __shared__ u16 Blds[BN * 32];
    const int tid  = threadIdx.x;
    const int wave = tid >> 6, lane = tid & 63;
    const int lr = lane & 15, lq = lane >> 4;
    const int wm = (wave >> 1) * 64, wn = (wave & 1) * (BN / 2);
    const int m0 = blockIdx.y * 128, n0 = blockIdx.x * BN;
    const int grow = tid >> 2;
    const int gcol = (tid & 3) * 8;
    const int woff = wave * 512;

    f32x4 zero = {0.f, 0.f, 0.f, 0.f};
    f32x4 acc[4][NJ];
    #pragma unroll
    for (int i = 0; i < 4; ++i)
        #pragma unroll
        for (int j = 0; j < NJ; ++j) acc[i][j] = zero;

    const u16* Ag = A + (size_t)m0 * lda;
    const u16* Wg = W + (size_t)n0 * ldw;

    for (int k0 = 0; k0 < K; k0 += 32) {
        GLD16(Ag + (size_t)grow * lda + k0 + gcol,        &Alds[woff]);
        GLD16(Ag + (size_t)(64 + grow) * lda + k0 + gcol, &Alds[2048 + woff]);
        GLD16(Wg + (size_t)grow * ldw + k0 + gcol,        &Blds[woff]);
        if (BN == 128)
            GLD16(Wg + (size_t)(64 + grow) * ldw + k0 + gcol, &Blds[2048 + woff]);
        __syncthreads();
        short8 af[4], bfr[NJ];
        #pragma unroll
        for (int i = 0; i < 4; ++i)
            af[i] = *(const short8*)&Alds[(wm + i * 16 + lr) * 32 + lq * 8];
        #pragma unroll
        for (int j = 0; j < NJ; ++j)
            bfr[j] = *(const short8*)&Blds[(wn + j * 16 + lr) * 32 + lq * 8];
        #pragma unroll
        for (int i = 0; i < 4; ++i)
            #pragma unroll
            for (int j = 0; j < NJ; ++j)
                acc[i][j] = __builtin_amdgcn_mfma_f32_16x16x32_bf16(af[i], bfr[j], acc[i][j], 0, 0, 0);
        __syncthreads();
    }

    #pragma unroll
    for (int i = 0; i < 4; ++i) {
        #pragma unroll
        for (int r = 0; r < 4; ++r) {
            int m = m0 + wm + i * 16 + lq * 4 + r;
            #pragma unroll
            for (int j = 0; j < NJ; ++j) {
                int n = n0 + wn + j * 16 + lr;
                float c = acc[i][j][r];
                if (bias)  c += bias[n];
                if (resid) c += resid[(size_t)m * ldr + n];
                if (relu)  c = fmaxf(c, 0.f);
                if (outf) outf[(size_t)m * ldcf + n] = c;
                if (outb) outb[(size_t)m * ldcb + n] = f2b(c);
            }
        }
    }
}

// ---------------- attention v6: MFMA flash, block per (b,h), 4 waves ----------
// LDS 80,448 B -> 2 blocks/CU; grid 512 -> all blocks co-resident (1 round).
// K[S][64] and V^T[64][S] staged once; per-wave P region (no barriers after
// the single staging sync). O written in-place into the Q slice.
__global__ __launch_bounds__(256)
void attn_kernel(u16* __restrict__ Q, int ldq, const u16* __restrict__ K, int ldk,
                 const u16* __restrict__ V, int ldv,
                 const int* __restrict__ mask, int T, int S, int causal, float rscale) {
    __shared__ u16 smem[SMEMU];
    u16* Kl = smem + KOFF;
    u16* Vt = smem + VOFF;
    u16* Pl = smem + POFF;

    const int bh = blockIdx.x;
    const int h = bh % H_SZ, b = bh / H_SZ;
    const int tid = threadIdx.x, wave = tid >> 6, lane = tid & 63;
    const int lm = lane & 15, quad = lane >> 4;

    const u16* Kg = K + (size_t)(b * S) * ldk + h * DK_SZ;
    const u16* Vg = V + (size_t)(b * S) * ldv + h * DK_SZ;
    u16* Qg = Q + (size_t)(b * T) * ldq + h * DK_SZ;

    const int stiles = (S + 15) >> 4;
    const int Scols = stiles << 4;
    const int Pcap = (Scols < PSTR) ? Scols : PSTR;

    // stage K (8B vector load + 8B LDS write) and V^T (8B load, 4 scalar writes)
    for (int i4 = tid * 4; i4 < S * DK_SZ; i4 += 1024) {
        int s = i4 >> 6, d = i4 & 63;
        u16x4 kv = *(const u16x4*)(Kg + (size_t)s * ldk + d);
        *(u16x4*)(Kl + s * KSTR + d) = kv;
        u16x4 vv = *(const u16x4*)(Vg + (size_t)s * ldv + d);
        Vt[(d + 0) * VSTR + s] = vv.x;
        Vt[(d + 1) * VSTR + s] = vv.y;
        Vt[(d + 2) * VSTR + s] = vv.z;
        Vt[(d + 3) * VSTR + s] = vv.w;
    }
    int pad = Scols - S;
    for (int i = tid; i < pad * DK_SZ; i += 256) {
        int d = i / pad, s = S + (i % pad);
        Vt[d * VSTR + s] = 0;
    }
    __syncthreads();

    const short8 zero8 = {0, 0, 0, 0, 0, 0, 0, 0};
    const f32x4 zerof = {0.f, 0.f, 0.f, 0.f};
    u16* Pw = Pl + wave * (16 * PSTR);

    for (int t0 = wave * 16; t0 < T; t0 += 64) {
        // Q A-fragments (global, 16B-aligned)
        int qr = t0 + lm; if (qr >= T) qr = T - 1;
        const u16* qrow = Qg + (size_t)qr * ldq;
        short8 qa0 = *(const short8*)(qrow + quad * 8);
        short8 qa1 = *(const short8*)(qrow + 32 + quad * 8);

        // QK^T
        f32x4 sc[13];
        #pragma unroll
        for (int st = 0; st < 13; ++st) if (st < stiles) {
            int srow = st * 16 + lm; if (srow >= S) srow = S - 1;
            const u16* kp = Kl + srow * KSTR + quad * 8;
            short8 kb0 = ld8(kp);
            short8 kb1 = ld8(kp + 32);
            f32x4 c = zerof;
            c = __builtin_amdgcn_mfma_f32_16x16x32_bf16(qa0, kb0, c, 0, 0, 0);
            c = __builtin_amdgcn_mfma_f32_16x16x32_bf16(qa1, kb1, c, 0, 0, 0);
            sc[st] = c;
        }

        // mask + scale + row max
        float mx[4] = {NEG_BIG, NEG_BIG, NEG_BIG, NEG_BIG};
        #pragma unroll
        for (int st = 0; st < 13; ++st) if (st < stiles) {
            int s = st * 16 + lm;
            int smi = (s < S) ? s : S - 1;
            #pragma unroll
            for (int r = 0; r < 4; ++r) {
                int t = t0 + quad * 4 + r;
                int tc = (t < T) ? t : T - 1;
                bool valid = (s < S) && (!causal || s <= t);
                if (valid && mask) valid = (mask[(size_t)(b * T + tc) * S + smi] != 1);
                float f = valid ? sc[st][r] * rscale : NEG_BIG;
                sc[st][r] = f;
                mx[r] = fmaxf(mx[r], f);
            }
        }
        #pragma unroll
        for (int r = 0; r < 4; ++r) {
            #pragma unroll
            for (int off = 1; off < 16; off <<= 1)
                mx[r] = fmaxf(mx[r], __shfl_xor(mx[r], off, 64));
        }

        // exp + sum + write P (bf16) to per-wave LDS
        float sum[4] = {0.f, 0.f, 0.f, 0.f};
        #pragma unroll
        for (int st = 0; st < 13; ++st) if (st < stiles) {
            int col = st * 16 + lm;
            #pragma unroll
            for (int r = 0; r < 4; ++r) {
                float p = __expf(sc[st][r] - mx[r]);
                sum[r] += p;
                if (col < PSTR) Pw[(quad * 4 + r) * PSTR + col] = f2b(p);
            }
        }
        float rden[4];
        #pragma unroll
        for (int r = 0; r < 4; ++r) {
            #pragma unroll
            for (int off = 1; off < 16; off <<= 1)
                sum[r] += __shfl_xor(sum[r], off, 64);
            rden[r] = (sum[r] > 0.f) ? 1.0f / sum[r] : 0.f;
        }

        // PV: O[m][d] = sum_s P[m][s] * Vt[d][s]
        f32x4 ov[4] = {zerof, zerof, zerof, zerof};
        for (int k0 = 0; k0 < Pcap; k0 += 32) {
            int nq = (Pcap - k0) >> 3;
            short8 pa = (quad < nq) ? ld8(Pw + lm * PSTR + k0 + quad * 8) : zero8;
            #pragma unroll
            for (int dt = 0; dt < 4; ++dt) {
                short8 vb = (quad < nq)
                    ? ld8(Vt + (dt * 16 + lm) * VSTR + k0 + quad * 8)
                    : zero8;
                ov[dt] = __builtin_amdgcn_mfma_f32_16x16x32_bf16(pa, vb, ov[dt], 0, 0, 0);
            }
        }

        // store O (in-place into Q slice)
        #pragma unroll
        for (int r = 0; r < 4; ++r) {
            int t = t0 + quad * 4 + r;
            if (t < T) {
                u16* orow = Qg + (size_t)t * ldq;
                #pragma unroll
                for (int dt = 0; dt < 4; ++dt)
                    orow[dt * 16 + lm] = f2b(ov[dt][r] * rden[r]);
            }
        }
    }
}

// ---------------- final logits: [rows,512](f32) @ ll_w[30,512]^T + b -> f32 ------
__global__ __launch_bounds__(256)
void logits_kernel(const float* __restrict__ X, const float* __restrict__ Wl,
                   const float* __restrict__ bl, float* __restrict__ out, int rows) {
    int idx = blockIdx.x * 256 + threadIdx.x;
    if (idx >= rows * V_SZ) return;
    int row = idx / V_SZ, v = idx % V_SZ;
    const f32x4* xr = (const f32x4*)(X + (size_t)row * D_MODEL);
    const f32x4* wr = (const f32x4*)(Wl + (size_t)v * D_MODEL);
    float acc = bl[v];
    #pragma unroll 4
    for (int k = 0; k < D_MODEL / 4; ++k) {
        f32x4 a = xr[k], w = wr[k];
        acc += a.x * w.x + a.y * w.y + a.z * w.z + a.w * w.w;
    }
    out[idx] = acc;
}

extern "C" void kernel_launch(void* const* d_in, const int* in_sizes, int n_in,
                              void* d_out, int out_size, void* d_ws, size_t ws_size,
                              hipStream_t stream) {
    const float* x          = (const float*)d_in[0];
    const float* y          = (const float*)d_in[1];
    const int*   x_mask     = (const int*)d_in[2];
    const int*   y_mask     = (const int*)d_in[3];
    const float* enc_qkv    = (const float*)d_in[4];
    const float* enc_proj_w = (const float*)d_in[5];
    const float* enc_proj_b = (const float*)d_in[6];
    const float* enc_ln1_g  = (const float*)d_in[7];
    const float* enc_ln1_b  = (const float*)d_in[8];
    const float* enc_ff_w1  = (const float*)d_in[9];
    const float* enc_ff_b1  = (const float*)d_in[10];
    const float* enc_ff_w2  = (const float*)d_in[11];
    const float* enc_ff_b2  = (const float*)d_in[12];
    const float* enc_ln2_g  = (const float*)d_in[13];
    const float* enc_ln2_b  = (const float*)d_in[14];
    const float* dec_sa_qkv    = (const float*)d_in[15];
    const float* dec_sa_proj_w = (const float*)d_in[16];
    const float* dec_sa_proj_b = (const float*)d_in[17];
    const float* dec_ln1_g  = (const float*)d_in[18];
    const float* dec_ln1_b  = (const float*)d_in[19];
    const float* dec_ca_qkv    = (const float*)d_in[20];
    const float* dec_ca_proj_w = (const float*)d_in[21];
    const float* dec_ca_proj_b = (const float*)d_in[22];
    const float* dec_ln2_g  = (const float*)d_in[23];
    const float* dec_ln2_b  = (const float*)d_in[24];
    const float* dec_ff_w1  = (const float*)d_in[25];
    const float* dec_ff_b1  = (const float*)d_in[26];
    const float* dec_ff_w2  = (const float*)d_in[27];
    const float* dec_ff_b2  = (const float*)d_in[28];
    const float* dec_ln3_g  = (const float*)d_in[29];
    const float* dec_ln3_b  = (const float*)d_in[30];
    const float* ll_w       = (const float*)d_in[31];
    const float* ll_b       = (const float*)d_in[32];

    const int ME = B_SZ * TX_SZ;   // 12800
    const int MD = B_SZ * TY_SZ;   // 6400
    const float rscale = 1.0f / sqrtf((float)D_MODEL);

    // ---- workspace ----
    char* base = (char*)d_ws;
    size_t off = 0;
    auto alloc = [&](size_t bytes) {
        void* p = base + off;
        off = (off + bytes + 63) & ~(size_t)63;
        return p;
    };
    float* A_enc = (float*)alloc((size_t)ME * D_MODEL * 4);
    float* A_dec = (float*)alloc((size_t)MD * D_MODEL * 4);
    float* N1f   = (float*)alloc((size_t)ME * D_MODEL * 4);
    u16*   N1b   = (u16*)  alloc((size_t)ME * D_MODEL * 2);
    u16*   NQb   = (u16*)  alloc((size_t)MD * D_MODEL * 2);
    u16*   BIG   = (u16*)  alloc((size_t)ME * DFF_SZ * 2);
    u16*   Wa    = (u16*)  alloc((size_t)DFF_SZ * D_MODEL * 2);
    u16*   Wb2   = (u16*)  alloc((size_t)DFF_SZ * D_MODEL * 2);
    u16* QKVb = BIG;                        // [M,1536]
    u16* Hb   = BIG;                        // [M,2048]
    u16* KVb  = BIG;                        // [ME,1024]
    u16* Qca  = BIG + (size_t)ME * 1024;    // [MD,512]

    auto castw = [&](const float* in, u16* out, int n) {
        int n4 = n / 4;
        hipLaunchKernelGGL(castw_kernel, dim3((n4 + 255) / 256), dim3(256), 0, stream, in, out, n4);
    };
    auto ln = [&](const float* in, const float* g, const float* b,
                  float* outf, u16* outb, int rows) {
        hipLaunchKernelGGL(ln_kernel, dim3(rows / 4), dim3(256), 0, stream, in, g, b, outf, outb, rows);
    };
    auto gemm = [&](const u16* A, int lda, const u16* W, int ldw, int M, int N, int K,
                    float* outf, int ldcf, u16* outb, int ldcb,
                    const float* bias, const float* resid, int ldr, int relu) {
        int blocks128 = (M / 128) * (N / 128);
        if (blocks128 < 256) {
            dim3 grid(N / 64, M / 128);
            hipLaunchKernelGGL((gemm_mfma_t<64>), grid, dim3(256), 0, stream,
                               A, lda, W, ldw, outf, ldcf, outb, ldcb, bias, resid, ldr, relu, K);
        } else {
            dim3 grid(N / 128, M / 128);
            hipLaunchKernelGGL((gemm_mfma_t<128>), grid, dim3(256), 0, stream,
                               A, lda, W, ldw, outf, ldcf, outb, ldcb, bias, resid, ldr, relu, K);
        }
    };
    auto attn = [&](u16* Q, int ldq, const u16* K, int ldk, const u16* V, int ldv,
                    const int* mask, int T, int S, int causal) {
        hipLaunchKernelGGL(attn_kernel, dim3(B_SZ * H_SZ), dim3(256), 0, stream,
                           Q, ldq, K, ldk, V, ldv, mask, T, S, causal, rscale);
    };

    const int WQKV = 3 * D_MODEL * D_MODEL;
    const int WDD  = D_MODEL * D_MODEL;
    const int WFF  = DFF_SZ * D_MODEL;

    // ---------------- encoder ----------------
    for (int l = 0; l < L_SZ; ++l) {
        const float* src = (l == 0) ? x : A_enc;
        castw(enc_qkv + (size_t)l * WQKV, Wa, WQKV);
        ln(src, enc_ln1_g + l * D_MODEL, enc_ln1_b + l * D_MODEL, N1f, N1b, ME);
        gemm(N1b, 512, Wa, 512, ME, 1536, 512, nullptr, 0, QKVb, 1536, nullptr, nullptr, 0, 0);
        attn(QKVb, 1536, QKVb + 512, 1536, QKVb + 1024, 1536, x_mask, TX_SZ, TX_SZ, 0);
        castw(enc_proj_w + (size_t)l * WDD, Wa, WDD);
        gemm(QKVb, 1536, Wa, 512, ME, 512, 512, A_enc, 512, nullptr, 0,
             enc_proj_b + l * D_MODEL, N1f, 512, 0);
        ln(A_enc, enc_ln2_g + l * D_MODEL, enc_ln2_b + l * D_MODEL, nullptr, N1b, ME);
        castw(enc_ff_w1 + (size_t)l * WFF, Wa, WFF);
        gemm(N1b, 512, Wa, 512, ME, 2048, 512, nullptr, 0, Hb, 2048,
             enc_ff_b1 + l * DFF_SZ, nullptr, 0, 1);
        castw(enc_ff_w2 + (size_t)l * WFF, Wb2, WFF);
        gemm(Hb, 2048, Wb2, 2048, ME, 512, 2048, A_enc, 512, nullptr, 0,
             enc_ff_b2 + l * D_MODEL, A_enc, 512, 0);
    }

    // ---------------- decoder ----------------
    for (int l = 0; l < L_SZ; ++l) {
        const float* src = (l == 0) ? y : A_dec;
        castw(dec_sa_qkv + (size_t)l * WQKV, Wa, WQKV);
        ln(src, dec_ln1_g + l * D_MODEL, dec_ln1_b + l * D_MODEL, N1f, N1b, MD);
        gemm(N1b, 512, Wa, 512, MD, 1536, 512, nullptr, 0, QKVb, 1536, nullptr, nullptr, 0, 0);
        attn(QKVb, 1536, QKVb + 512, 1536, QKVb + 1024, 1536, y_mask, TY_SZ, TY_SZ, 1);
        castw(dec_sa_proj_w + (size_t)l * WDD, Wa, WDD);
        gemm(QKVb, 1536, Wa, 512, MD, 512, 512, A_dec, 512, nullptr, 0,
             dec_sa_proj_b + l * D_MODEL, N1f, 512, 0);
        // cross-attention
        ln(A_enc, dec_ln2_g + l * D_MODEL, dec_ln2_b + l * D_MODEL, nullptr, N1b, ME);
        ln(A_dec, dec_ln2_g + l * D_MODEL, dec_ln2_b + l * D_MODEL, N1f, NQb, MD);
        castw(dec_ca_qkv + (size_t)l * WQKV, Wa, WDD);           // Q weights
        gemm(NQb, 512, Wa, 512, MD, 512, 512, nullptr, 0, Qca, 512, nullptr, nullptr, 0, 0);
        castw(dec_ca_qkv + (size_t)l * WQKV + WDD, Wa, 2 * WDD); // K,V weights
        gemm(N1b, 512, Wa, 512, ME, 1024, 512, nullptr, 0, KVb, 1024, nullptr, nullptr, 0, 0);
        attn(Qca, 512, KVb, 1024, KVb + 512, 1024, nullptr, TY_SZ, TX_SZ, 0);
        castw(dec_ca_proj_w + (size_t)l * WDD, Wa, WDD);
        gemm(Qca, 512, Wa, 512, MD, 512, 512, A_dec, 512, nullptr, 0,
             dec_ca_proj_b + l * D_MODEL, N1f, 512, 0);
        // FF
        ln(A_dec, dec_ln3_g + l * D_MODEL, dec_ln3_b + l * D_MODEL, nullptr, N1b, MD);
        castw(dec_ff_w1 + (size_t)l * WFF, Wa, WFF);
        gemm(N1b, 512, Wa, 512, MD, 2048, 512, nullptr, 0, Hb, 2048,
             dec_ff_b1 + l * DFF_SZ, nullptr, 0, 1);
        castw(dec_ff_w2 + (size_t)l * WFF, Wb2, WFF);
        gemm(Hb, 2048, Wb2, 2048, MD, 512, 2048, A_dec, 512, nullptr, 0,
             dec_ff_b2 + l * D_MODEL, A_dec, 512, 0);
    }

    // ---------------- final projection ----------------
    {
        int total = MD * V_SZ;
        hipLaunchKernelGGL(logits_kernel, dim3((total + 255) / 256), dim3(256), 0, stream,
                           A_dec, ll_w, ll_b, (float*)d_out, MD);
    }
    (void)in_sizes; (void)n_in; (void)out_size; (void)ws_size;
}